// Round 1
// baseline (3677.332 us; speedup 1.0000x reference)
//
#include <hip/hip_runtime.h>
#include <hip/hip_bf16.h>
#include <math.h>

// ---------------------------------------------------------------------------
// DiffTransformer block, fp32 baseline (correctness anchor).
// B=1, S=2048, E=1024, H=16, D=32, SIG=256.
// All GEMMs: C[M,N] = A[M,K] @ B[N,K]^T   (weights are [N,K] row-major).
// ---------------------------------------------------------------------------

#define S_LEN 2048
#define E_DIM 1024
#define H_NUM 16
#define D_DIM 32
#define SIG_DIM 256

// LAMBDA_INIT = 0.8 - 0.6*exp(-0.3)
#define LAMBDA_INIT 0.3555090675909693f
#define ONE_MINUS_LAMBDA_INIT 0.6444909324090307f

// ---- workspace layout (floats) --------------------------------------------
// Q   [0, 6291456)            qkv 2048x3072              (dead after attn)
// A   [6291456, 10485760)     attn 2 x 2048 x 1024       (dead after diffnorm)
// T1  [6291456, 8388608)      out-proj + x  (overlays A; A dead by then)
// G   [0, 8388608)            silu(ff1)     (overlays Q,T1; both dead by then)
// N   [10485760, 12582912)    a_norm;  later T2 = ff2+h  (a_norm dead by then)
// H   [12582912, 14680064)    h = ln1(...)
// TAB [14680064, ...)         cos 16384 | sin 16384 | sig 32 | lam 1
// total ~58.9 MB
static const size_t Q_OFF   = 0;
static const size_t A_OFF   = 6291456;
static const size_t T1_OFF  = 6291456;
static const size_t G_OFF   = 0;
static const size_t N_OFF   = 10485760;
static const size_t T2_OFF  = 10485760;
static const size_t H_OFF   = 12582912;
static const size_t TAB_OFF = 14680064;
static const size_t SIG_SUB = 32768;   // within TAB
static const size_t LAM_SUB = 32800;   // within TAB

// ---------------------------------------------------------------------------
// cos/sin table: freqs[t][i] = t * 10000^(-i/8), i in [0,8)
// computed in double to sidestep fp32 pow accumulation issues.
// ---------------------------------------------------------------------------
__global__ __launch_bounds__(256) void tab_kernel(float* __restrict__ tab) {
    int t = blockIdx.x * 256 + threadIdx.x;     // 0..16383
    int s = t >> 3;
    int pi = t & 7;
    double inv = pow(10000.0, -(double)pi / 8.0);
    double ph = (double)s * inv;
    tab[t]          = (float)cos(ph);
    tab[16384 + t]  = (float)sin(ph);
}

// ---------------------------------------------------------------------------
// sig[d] = emb . sigma_w[d,:]   (d<32);  lam scalar
// ---------------------------------------------------------------------------
__global__ __launch_bounds__(64) void sig_lam_kernel(
    const float* __restrict__ emb, const float* __restrict__ sigma_w,
    const float* __restrict__ lq1, const float* __restrict__ lk1,
    const float* __restrict__ lq2, const float* __restrict__ lk2,
    float* __restrict__ sig, float* __restrict__ lam)
{
    int t = threadIdx.x;
    if (t < 32) {
        float acc = 0.f;
        for (int j = 0; j < SIG_DIM; ++j)
            acc = fmaf(emb[j], sigma_w[t * SIG_DIM + j], acc);
        sig[t] = acc;
    } else if (t == 32) {
        float s1 = 0.f, s2 = 0.f;
        for (int d = 0; d < D_DIM; ++d) {
            s1 = fmaf(lq1[d], lk1[d], s1);
            s2 = fmaf(lq2[d], lk2[d], s2);
        }
        lam[0] = expf(s1) - expf(s2) + LAMBDA_INIT;
    }
}

// ---------------------------------------------------------------------------
// Generic fp32 GEMM: C[M,N] = A[M,K] @ B[N,K]^T (+bias) (silu) (+res)
// 128 x TBN tile, BK=16, 256 threads, 8 x (TBN/16) per-thread tile.
// M%128==0, N%TBN==0, K%16==0 assumed (true for all calls here).
// ---------------------------------------------------------------------------
template<int TBN>
__global__ __launch_bounds__(256) void gemm_kernel(
    const float* __restrict__ A, const float* __restrict__ B,
    float* __restrict__ C, int M, int N, int K,
    const float* __restrict__ bias, const float* __restrict__ res,
    int do_silu)
{
    constexpr int TBM = 128;
    constexpr int TBK = 16;
    constexpr int TN  = TBN / 16;      // 8 or 4
    __shared__ float As[TBK][TBM + 4];
    __shared__ float Bs[TBK][TBN + 4];

    const int tid = threadIdx.x;
    const int tx = tid & 15;
    const int ty = tid >> 4;
    const int m0 = blockIdx.y * TBM;
    const int n0 = blockIdx.x * TBN;

    float acc[8][TN];
#pragma unroll
    for (int i = 0; i < 8; ++i)
#pragma unroll
        for (int j = 0; j < TN; ++j) acc[i][j] = 0.f;

    const int arow = tid >> 2;            // 0..63
    const int akk  = (tid & 3) << 2;      // 0,4,8,12
    const float* Ap = A + (size_t)(m0 + arow) * K + akk;
    const float* Bp = B + (size_t)(n0 + arow) * K + akk;

    for (int k0 = 0; k0 < K; k0 += TBK) {
        float4 a0 = *(const float4*)(Ap + k0);
        float4 a1 = *(const float4*)(Ap + (size_t)64 * K + k0);
        float4 b0 = *(const float4*)(Bp + k0);
        float4 b1;
        if constexpr (TBN == 128) b1 = *(const float4*)(Bp + (size_t)64 * K + k0);

        __syncthreads();
        As[akk + 0][arow] = a0.x; As[akk + 1][arow] = a0.y;
        As[akk + 2][arow] = a0.z; As[akk + 3][arow] = a0.w;
        As[akk + 0][arow + 64] = a1.x; As[akk + 1][arow + 64] = a1.y;
        As[akk + 2][arow + 64] = a1.z; As[akk + 3][arow + 64] = a1.w;
        Bs[akk + 0][arow] = b0.x; Bs[akk + 1][arow] = b0.y;
        Bs[akk + 2][arow] = b0.z; Bs[akk + 3][arow] = b0.w;
        if constexpr (TBN == 128) {
            Bs[akk + 0][arow + 64] = b1.x; Bs[akk + 1][arow + 64] = b1.y;
            Bs[akk + 2][arow + 64] = b1.z; Bs[akk + 3][arow + 64] = b1.w;
        }
        __syncthreads();

#pragma unroll
        for (int kk = 0; kk < TBK; ++kk) {
            float af[8], bf[TN];
            *(float4*)&af[0] = *(const float4*)&As[kk][ty * 8];
            *(float4*)&af[4] = *(const float4*)&As[kk][ty * 8 + 4];
            *(float4*)&bf[0] = *(const float4*)&Bs[kk][tx * TN];
            if constexpr (TN == 8)
                *(float4*)&bf[4] = *(const float4*)&Bs[kk][tx * TN + 4];
#pragma unroll
            for (int i = 0; i < 8; ++i)
#pragma unroll
                for (int j = 0; j < TN; ++j)
                    acc[i][j] = fmaf(af[i], bf[j], acc[i][j]);
        }
    }

#pragma unroll
    for (int i = 0; i < 8; ++i) {
        int m = m0 + ty * 8 + i;
        float* crow = C + (size_t)m * N + n0 + tx * TN;
        const float* rrow = res ? (res + (size_t)m * N + n0 + tx * TN) : (const float*)0;
#pragma unroll
        for (int j = 0; j < TN; ++j) {
            float v = acc[i][j];
            if (bias) v += bias[n0 + tx * TN + j];
            if (do_silu) v = v / (1.0f + expf(-v));
            if (res) v += rrow[j];
            crow[j] = v;
        }
    }
}

// ---------------------------------------------------------------------------
// RoPE (first 16 dims of each 32-dim rope-head, interleaved pairs) applied
// in-place to q and k parts of qkv; then sig added to odd rope-heads (sub 1).
// thread = (s, part(q/k), rh)
// ---------------------------------------------------------------------------
__global__ __launch_bounds__(256) void rope_kernel(
    float* __restrict__ qkv, const float* __restrict__ tab,
    const float* __restrict__ sig)
{
    int t = blockIdx.x * 256 + threadIdx.x;   // 0..131071
    int s    = t >> 6;
    int sub  = t & 63;
    int part = sub >> 5;    // 0=q, 1=k
    int rh   = sub & 31;
    float* p = qkv + (size_t)s * 3072 + part * E_DIM + rh * D_DIM;
    const float* ct = tab + s * 8;
    const float* st = tab + 16384 + s * 8;

    float v[16];
#pragma unroll
    for (int i = 0; i < 4; ++i) *(float4*)(v + i * 4) = *(const float4*)(p + i * 4);
    float o[16];
#pragma unroll
    for (int pi = 0; pi < 8; ++pi) {
        float c = ct[pi], sn = st[pi];
        float x1 = v[2 * pi], x2 = v[2 * pi + 1];
        o[2 * pi]     = x1 * c - x2 * sn;
        o[2 * pi + 1] = x2 * c + x1 * sn;
    }
    if (rh & 1) {
#pragma unroll
        for (int i = 0; i < 16; ++i) o[i] += sig[i];
        float u[16];
#pragma unroll
        for (int i = 0; i < 4; ++i) *(float4*)(u + i * 4) = *(const float4*)(p + 16 + i * 4);
#pragma unroll
        for (int i = 0; i < 16; ++i) u[i] += sig[16 + i];
#pragma unroll
        for (int i = 0; i < 4; ++i) *(float4*)(p + 16 + i * 4) = *(const float4*)(u + i * 4);
    }
#pragma unroll
    for (int i = 0; i < 4; ++i) *(float4*)(p + i * 4) = *(const float4*)(o + i * 4);
}

// ---------------------------------------------------------------------------
// Dual causal attention, online softmax, thread-per-query-row.
// block = 64 threads (1 wave) = 64 consecutive rows of one (a, h).
// k/v addresses are wave-uniform -> scalar-load broadcast.
// acc[0..63] accumulates [p@v1 | p@v2] (contiguous 64 floats of v head h).
// ---------------------------------------------------------------------------
__global__ __launch_bounds__(64) void attn_kernel(
    const float* __restrict__ qkv, float* __restrict__ attn)
{
    int bid = blockIdx.x;          // 0..1023
    int rb = bid & 31;
    int h  = (bid >> 5) & 15;
    int a  = bid >> 9;
    int lane = threadIdx.x;
    int i = rb * 64 + lane;
    int rh = 2 * h + a;

    const float* qp = qkv + (size_t)i * 3072 + rh * D_DIM;
    float q[32];
#pragma unroll
    for (int d = 0; d < 8; ++d) *(float4*)(q + d * 4) = *(const float4*)(qp + d * 4);

    float acc[64];
#pragma unroll
    for (int d = 0; d < 64; ++d) acc[d] = 0.f;
    float m = -3.0e38f, l = 0.f;
    const float scale = 0.17677669529663687f;  // 32^-0.5

    const float* kbase = qkv + E_DIM + rh * D_DIM;
    const float* vbase = qkv + 2 * E_DIM + h * 64;
    int jmax = rb * 64 + 63;

    for (int j = 0; j <= jmax; ++j) {
        const float* kp = kbase + (size_t)j * 3072;
        float d0 = 0.f, d1 = 0.f, d2 = 0.f, d3 = 0.f;
#pragma unroll
        for (int dd = 0; dd < 32; dd += 4) {
            d0 = fmaf(q[dd],     kp[dd],     d0);
            d1 = fmaf(q[dd + 1], kp[dd + 1], d1);
            d2 = fmaf(q[dd + 2], kp[dd + 2], d2);
            d3 = fmaf(q[dd + 3], kp[dd + 3], d3);
        }
        float sc = ((d0 + d1) + (d2 + d3)) * scale;
        if (j <= i) {
            if (sc > m) {
                float corr = __expf(m - sc);
                l *= corr;
#pragma unroll
                for (int d = 0; d < 64; ++d) acc[d] *= corr;
                m = sc;
            }
            float p = __expf(sc - m);
            l += p;
            const float* vp = vbase + (size_t)j * 3072;
#pragma unroll
            for (int d = 0; d < 64; ++d) acc[d] = fmaf(p, vp[d], acc[d]);
        }
    }

    float rl = 1.0f / l;
    float* op = attn + ((size_t)a * S_LEN + i) * E_DIM + h * 64;
#pragma unroll
    for (int d = 0; d < 64; d += 4) {
        float4 o;
        o.x = acc[d] * rl; o.y = acc[d + 1] * rl;
        o.z = acc[d + 2] * rl; o.w = acc[d + 3] * rl;
        *(float4*)(op + d) = o;
    }
}

// ---------------------------------------------------------------------------
// c = attn1 - lam*attn2 ; rmsnorm over 64 (eps 1e-8) * ln_w + ln_b ;
// * (1 - LAMBDA_INIT).  One wave per (s,h) group.
// ---------------------------------------------------------------------------
__global__ __launch_bounds__(256) void diffnorm_kernel(
    const float* __restrict__ attn, const float* __restrict__ ln_w,
    const float* __restrict__ ln_b, const float* __restrict__ lamp,
    float* __restrict__ out)
{
    int g = blockIdx.x * 4 + (threadIdx.x >> 6);   // 0..32767
    int lane = threadIdx.x & 63;
    int s = g >> 4;
    int h = g & 15;
    float lam = lamp[0];
    const float* p1 = attn + (size_t)s * E_DIM + h * 64;
    const float* p2 = attn + (size_t)(S_LEN + s) * E_DIM + h * 64;
    float c = p1[lane] - lam * p2[lane];
    float sq = c * c;
#pragma unroll
    for (int off = 32; off >= 1; off >>= 1) sq += __shfl_xor(sq, off, 64);
    float ms = sq * (1.0f / 64.0f);
    float r = 1.0f / sqrtf(ms + 1e-8f);
    float o = (c * r * ln_w[lane] + ln_b[lane]) * ONE_MINUS_LAMBDA_INIT;
    out[(size_t)s * E_DIM + h * 64 + lane] = o;
}

// ---------------------------------------------------------------------------
// LayerNorm over E=1024, eps 1e-5. One block (256 thr) per row, float4/thr.
// ---------------------------------------------------------------------------
__global__ __launch_bounds__(256) void ln_kernel(
    const float* __restrict__ in, const float* __restrict__ w,
    const float* __restrict__ b, float* __restrict__ out)
{
    __shared__ float red[4];
    int row = blockIdx.x;
    int t = threadIdx.x;
    const float* xr = in + (size_t)row * E_DIM + t * 4;
    float4 v = *(const float4*)xr;
    float s = v.x + v.y + v.z + v.w;
#pragma unroll
    for (int off = 32; off >= 1; off >>= 1) s += __shfl_xor(s, off, 64);
    if ((t & 63) == 0) red[t >> 6] = s;
    __syncthreads();
    float mu = (red[0] + red[1] + red[2] + red[3]) * (1.0f / 1024.0f);
    __syncthreads();
    float dx0 = v.x - mu, dx1 = v.y - mu, dx2 = v.z - mu, dx3 = v.w - mu;
    float sq = dx0 * dx0 + dx1 * dx1 + dx2 * dx2 + dx3 * dx3;
#pragma unroll
    for (int off = 32; off >= 1; off >>= 1) sq += __shfl_xor(sq, off, 64);
    if ((t & 63) == 0) red[t >> 6] = sq;
    __syncthreads();
    float var = (red[0] + red[1] + red[2] + red[3]) * (1.0f / 1024.0f);
    float r = 1.0f / sqrtf(var + 1e-5f);
    float4 wv = *(const float4*)(w + t * 4);
    float4 bv = *(const float4*)(b + t * 4);
    float4 o;
    o.x = dx0 * r * wv.x + bv.x;
    o.y = dx1 * r * wv.y + bv.y;
    o.z = dx2 * r * wv.z + bv.z;
    o.w = dx3 * r * wv.w + bv.w;
    *(float4*)(out + (size_t)row * E_DIM + t * 4) = o;
}

// ---------------------------------------------------------------------------
extern "C" void kernel_launch(void* const* d_in, const int* in_sizes, int n_in,
                              void* d_out, int out_size, void* d_ws, size_t ws_size,
                              hipStream_t stream)
{
    const float* x       = (const float*)d_in[0];
    const float* emb     = (const float*)d_in[1];
    const float* qkv_w   = (const float*)d_in[2];
    const float* out_w   = (const float*)d_in[3];
    const float* sigma_w = (const float*)d_in[4];
    const float* lq1     = (const float*)d_in[5];
    const float* lk1     = (const float*)d_in[6];
    const float* lq2     = (const float*)d_in[7];
    const float* lk2     = (const float*)d_in[8];
    const float* ln_w    = (const float*)d_in[9];
    const float* ln_b    = (const float*)d_in[10];
    const float* ln1_w   = (const float*)d_in[11];
    const float* ln1_b   = (const float*)d_in[12];
    const float* ln2_w   = (const float*)d_in[13];
    const float* ln2_b   = (const float*)d_in[14];
    const float* w1      = (const float*)d_in[15];
    const float* b1      = (const float*)d_in[16];
    const float* w2      = (const float*)d_in[17];
    const float* b2      = (const float*)d_in[18];
    float* out = (float*)d_out;
    float* ws  = (float*)d_ws;

    float* qkv  = ws + Q_OFF;
    float* attn = ws + A_OFF;
    float* t1   = ws + T1_OFF;
    float* g    = ws + G_OFF;
    float* anrm = ws + N_OFF;
    float* t2   = ws + T2_OFF;
    float* hbuf = ws + H_OFF;
    float* tab  = ws + TAB_OFF;
    float* sig  = tab + SIG_SUB;
    float* lam  = tab + LAM_SUB;

    // 1. cos/sin tables
    tab_kernel<<<64, 256, 0, stream>>>(tab);
    // 2. sig + lambda
    sig_lam_kernel<<<1, 64, 0, stream>>>(emb, sigma_w, lq1, lk1, lq2, lk2, sig, lam);
    // 3. qkv = x @ qkv_w^T        (2048 x 3072 x 1024)
    gemm_kernel<128><<<dim3(3072 / 128, 2048 / 128), 256, 0, stream>>>(
        x, qkv_w, qkv, 2048, 3072, 1024, (const float*)0, (const float*)0, 0);
    // 4. RoPE + sigma add (in place on q,k)
    rope_kernel<<<512, 256, 0, stream>>>(qkv, tab, sig);
    // 5. dual causal attention
    attn_kernel<<<1024, 64, 0, stream>>>(qkv, attn);
    // 6. diff + rmsnorm + scale
    diffnorm_kernel<<<8192, 256, 0, stream>>>(attn, ln_w, ln_b, lam, anrm);
    // 7. t1 = a_norm @ out_w^T + x     (2048 x 1024 x 1024)
    gemm_kernel<64><<<dim3(1024 / 64, 2048 / 128), 256, 0, stream>>>(
        anrm, out_w, t1, 2048, 1024, 1024, (const float*)0, x, 0);
    // 8. h = layernorm(t1)
    ln_kernel<<<2048, 256, 0, stream>>>(t1, ln1_w, ln1_b, hbuf);
    // 9. g = silu(h @ w1^T + b1)       (2048 x 4096 x 1024)
    gemm_kernel<128><<<dim3(4096 / 128, 2048 / 128), 256, 0, stream>>>(
        hbuf, w1, g, 2048, 4096, 1024, b1, (const float*)0, 1);
    // 10. t2 = g @ w2^T + b2 + h       (2048 x 1024 x 4096)
    gemm_kernel<64><<<dim3(1024 / 64, 2048 / 128), 256, 0, stream>>>(
        g, w2, t2, 2048, 1024, 4096, b2, hbuf, 0);
    // 11. out = layernorm(t2)
    ln_kernel<<<2048, 256, 0, stream>>>(t2, ln2_w, ln2_b, out);
}

// Round 5
// 781.965 us; speedup vs baseline: 4.7027x; 4.7027x over previous
//
#include <hip/hip_runtime.h>
#include <hip/hip_bf16.h>
#include <math.h>

// ---------------------------------------------------------------------------
// DiffTransformer block. B=1, S=2048, E=1024, H=16, D=32, SIG=256.
// Round 5 (= round 2 design; rounds 2-4 hit infra GPU timeouts, never ran):
// bf16 MFMA GEMMs (m97 structure) + wave-parallel LDS-staged attention.
// All GEMMs: C[M,N] = A[M,K] @ B[N,K]^T (weights row-major [N,K]).
// ---------------------------------------------------------------------------

#define S_LEN 2048
#define E_DIM 1024
#define H_NUM 16
#define D_DIM 32
#define SIG_DIM 256

#define LAMBDA_INIT 0.3555090675909693f
#define ONE_MINUS_LAMBDA_INIT 0.6444909324090307f

typedef __bf16 v8bf __attribute__((ext_vector_type(8)));
typedef __bf16 v4bf __attribute__((ext_vector_type(4)));
typedef float f32x4 __attribute__((ext_vector_type(4)));
static_assert(sizeof(v8bf) == 16, "v8bf must be 16B");

// ---- workspace layout (BYTE offsets) --------------------------------------
// [0,        25165824)  qkv f32           -> owb bf16 / w1b bf16 / w2b bf16 (after attn)
// [8388608,  25165824)  g bf16 (ff1 out, after qkv dead)
// [25165824, 29360128)  xb bf16           -> attn a0 f32 -> t1 f32
// [25165824, 41943040)  attn f32 (a0|a1)
// [33554432, 37748736)  hb bf16 (after attn a1 dead)  -> t2 f32 region
// [33554432, 41943040)  t2 f32 (after hb dead)
// [41943040, 46137344)  anrm bf16         -> hbuf f32
// [41943040, 50331648)  hbuf f32
// [50331648, 56623104)  qwb bf16
// [56623104, 56754308)  tab: cos[16384] sin[16384] f32, sig[32], lam[1]
// peak ~56.8 MB (round-1 used 58.9 MB OK)
#define B_QKV   0
#define B_G     8388608
#define B_XB    25165824
#define B_ATTN  25165824
#define B_T1    25165824
#define B_HB    33554432
#define B_T2    33554432
#define B_ANRM  41943040
#define B_HBUF  41943040
#define B_QWB   50331648
#define B_OWB   0
#define B_W1B   0
#define B_W2B   0
#define B_TAB   56623104

// ---------------------------------------------------------------------------
__global__ __launch_bounds__(256) void tab_kernel(float* __restrict__ tab) {
    int t = blockIdx.x * 256 + threadIdx.x;     // 0..16383
    int s = t >> 3;
    int pi = t & 7;
    double inv = pow(10000.0, -(double)pi / 8.0);
    double ph = (double)s * inv;
    tab[t]         = (float)cos(ph);
    tab[16384 + t] = (float)sin(ph);
}

__global__ __launch_bounds__(64) void sig_lam_kernel(
    const float* __restrict__ emb, const float* __restrict__ sigma_w,
    const float* __restrict__ lq1, const float* __restrict__ lk1,
    const float* __restrict__ lq2, const float* __restrict__ lk2,
    float* __restrict__ sig, float* __restrict__ lam)
{
    int t = threadIdx.x;
    if (t < 32) {
        float acc = 0.f;
        for (int j = 0; j < SIG_DIM; ++j)
            acc = fmaf(emb[j], sigma_w[t * SIG_DIM + j], acc);
        sig[t] = acc;
    } else if (t == 32) {
        float s1 = 0.f, s2 = 0.f;
        for (int d = 0; d < D_DIM; ++d) {
            s1 = fmaf(lq1[d], lk1[d], s1);
            s2 = fmaf(lq2[d], lk2[d], s2);
        }
        lam[0] = expf(s1) - expf(s2) + LAMBDA_INIT;
    }
}

// ---------------------------------------------------------------------------
// f32 -> bf16 conversion, 8 elems/thread. n must be a multiple of 2048.
// ---------------------------------------------------------------------------
__global__ __launch_bounds__(256) void f2b_kernel(
    const float* __restrict__ in, __bf16* __restrict__ out, int n)
{
    int base = (blockIdx.x * 256 + threadIdx.x) * 8;
    if (base >= n) return;
    float4 v0 = *(const float4*)(in + base);
    float4 v1 = *(const float4*)(in + base + 4);
    v8bf o;
    o[0] = (__bf16)v0.x; o[1] = (__bf16)v0.y; o[2] = (__bf16)v0.z; o[3] = (__bf16)v0.w;
    o[4] = (__bf16)v1.x; o[5] = (__bf16)v1.y; o[6] = (__bf16)v1.z; o[7] = (__bf16)v1.w;
    *(v8bf*)(out + base) = o;
}

// ---------------------------------------------------------------------------
// bf16 MFMA GEMM (m97 structure): 128x128 tile, BK=32, 256 thr (4 waves),
// global_load_lds dwordx4 staging, 16x16x32 bf16 MFMA, 4x4 frags/wave.
// C[M,N] = A[M,K] @ B[N,K]^T. Epilogue: (+bias)(silu)(+res), f32 or bf16 out.
// ---------------------------------------------------------------------------
__device__ __forceinline__ void gload_lds16(const __bf16* g, __bf16* l) {
    __builtin_amdgcn_global_load_lds(
        (const __attribute__((address_space(1))) unsigned int*)g,
        (__attribute__((address_space(3))) unsigned int*)l, 16, 0, 0);
}

template<bool BIAS, bool SILU, bool RES, bool OBF16>
__global__ __launch_bounds__(256) void mgemm_kernel(
    const __bf16* __restrict__ A, const __bf16* __restrict__ B,
    float* __restrict__ C, __bf16* __restrict__ Cb,
    int M, int N, int K,
    const float* __restrict__ bias, const float* __restrict__ res)
{
    __shared__ __bf16 As[128][32];
    __shared__ __bf16 Bs[128][32];

    const int tid  = threadIdx.x;
    const int wid  = tid >> 6;
    const int lane = tid & 63;
    const int m0 = blockIdx.y * 128;
    const int n0 = blockIdx.x * 128;
    const int wr = (wid >> 1) * 64;
    const int wc = (wid & 1) * 64;
    const int lrow = lane & 15;
    const int kg   = lane >> 4;        // 0..3

    f32x4 acc[4][4];
#pragma unroll
    for (int mi = 0; mi < 4; ++mi)
#pragma unroll
        for (int ni = 0; ni < 4; ++ni) acc[mi][ni] = (f32x4){0.f, 0.f, 0.f, 0.f};

    const int srow = lane >> 2;        // 0..15
    const int sfi  = lane & 3;
    const __bf16* Ap0 = A + (size_t)(m0 + wid * 16 + srow) * K + sfi * 8;
    const __bf16* Ap1 = Ap0 + (size_t)64 * K;
    const __bf16* Bp0 = B + (size_t)(n0 + wid * 16 + srow) * K + sfi * 8;
    const __bf16* Bp1 = Bp0 + (size_t)64 * K;
    __bf16* Al0 = &As[wid * 16][0];
    __bf16* Al1 = &As[64 + wid * 16][0];
    __bf16* Bl0 = &Bs[wid * 16][0];
    __bf16* Bl1 = &Bs[64 + wid * 16][0];

    for (int k0 = 0; k0 < K; k0 += 32) {
        __syncthreads();
        gload_lds16(Ap0 + k0, Al0);
        gload_lds16(Ap1 + k0, Al1);
        gload_lds16(Bp0 + k0, Bl0);
        gload_lds16(Bp1 + k0, Bl1);
        __syncthreads();

        v8bf a[4], b[4];
#pragma unroll
        for (int mi = 0; mi < 4; ++mi)
            a[mi] = *(const v8bf*)&As[wr + mi * 16 + lrow][kg * 8];
#pragma unroll
        for (int ni = 0; ni < 4; ++ni)
            b[ni] = *(const v8bf*)&Bs[wc + ni * 16 + lrow][kg * 8];
#pragma unroll
        for (int mi = 0; mi < 4; ++mi)
#pragma unroll
            for (int ni = 0; ni < 4; ++ni)
                acc[mi][ni] = __builtin_amdgcn_mfma_f32_16x16x32_bf16(
                    a[mi], b[ni], acc[mi][ni], 0, 0, 0);
    }

    const int crow = (lane >> 4) * 4;
    const int ccol = lane & 15;
#pragma unroll
    for (int mi = 0; mi < 4; ++mi) {
#pragma unroll
        for (int ni = 0; ni < 4; ++ni) {
            const int col = n0 + wc + ni * 16 + ccol;
            float bv = 0.f;
            if (BIAS) bv = bias[col];
#pragma unroll
            for (int j = 0; j < 4; ++j) {
                const int row = m0 + wr + mi * 16 + crow + j;
                float v = acc[mi][ni][j] + bv;
                if (SILU) v = v / (1.f + expf(-v));
                if (RES) v += res[(size_t)row * N + col];
                if (OBF16) Cb[(size_t)row * N + col] = (__bf16)v;
                else       C[(size_t)row * N + col] = v;
            }
        }
    }
}

// ---------------------------------------------------------------------------
// RoPE in-place on q,k of qkv + sig add to odd rope-heads.
// ---------------------------------------------------------------------------
__global__ __launch_bounds__(256) void rope_kernel(
    float* __restrict__ qkv, const float* __restrict__ tab,
    const float* __restrict__ sig)
{
    int t = blockIdx.x * 256 + threadIdx.x;   // 0..131071
    int s    = t >> 6;
    int sub  = t & 63;
    int part = sub >> 5;    // 0=q, 1=k
    int rh   = sub & 31;
    float* p = qkv + (size_t)s * 3072 + part * E_DIM + rh * D_DIM;
    const float* ct = tab + s * 8;
    const float* st = tab + 16384 + s * 8;

    float v[16];
#pragma unroll
    for (int i = 0; i < 4; ++i) *(float4*)(v + i * 4) = *(const float4*)(p + i * 4);
    float o[16];
#pragma unroll
    for (int pi = 0; pi < 8; ++pi) {
        float c = ct[pi], sn = st[pi];
        float x1 = v[2 * pi], x2 = v[2 * pi + 1];
        o[2 * pi]     = x1 * c - x2 * sn;
        o[2 * pi + 1] = x2 * c + x1 * sn;
    }
    if (rh & 1) {
#pragma unroll
        for (int i = 0; i < 16; ++i) o[i] += sig[i];
        float u[16];
#pragma unroll
        for (int i = 0; i < 4; ++i) *(float4*)(u + i * 4) = *(const float4*)(p + 16 + i * 4);
#pragma unroll
        for (int i = 0; i < 16; ++i) u[i] += sig[16 + i];
#pragma unroll
        for (int i = 0; i < 4; ++i) *(float4*)(p + 16 + i * 4) = *(const float4*)(u + i * 4);
    }
#pragma unroll
    for (int i = 0; i < 4; ++i) *(float4*)(p + i * 4) = *(const float4*)(o + i * 4);
}

// ---------------------------------------------------------------------------
// Dual causal attention. Block = 256 thr = 64 rows x 4 j-splits (sub = tid&3).
// K/V tiles (64 j-rows) staged in LDS, XOR-swizzled float4 slots so the 4
// adjacent-j readers hit distinct banks; 16 same-j lanes broadcast.
// Per-sub online softmax, merged via shfl_xor(1,2) butterfly at the end.
// ---------------------------------------------------------------------------
__global__ __launch_bounds__(256, 2) void attn_kernel(
    const float* __restrict__ qkv, float* __restrict__ attn)
{
    __shared__ float4 Ks[512];    // [64 rows][8 f4], slot = row*8  + (fi ^ (row&7))
    __shared__ float4 Vs[1024];   // [64 rows][16 f4], slot = row*16 + (fi ^ ((row&7)<<1))

    const int bid = blockIdx.x;          // 0..1023
    const int rb = bid >> 5;             // row tile 0..31
    const int ah = bid & 31;
    const int h = ah >> 1;
    const int a = ah & 1;
    const int tid = threadIdx.x;
    const int r = tid >> 2;
    const int sub = tid & 3;
    const int i0 = rb * 64;
    const int i = i0 + r;
    const int rh = 2 * h + a;

    const float* qp = qkv + (size_t)i * 3072 + rh * D_DIM;
    float q[32];
#pragma unroll
    for (int d = 0; d < 8; ++d) *(float4*)(q + d * 4) = *(const float4*)(qp + d * 4);

    float acc[64];
#pragma unroll
    for (int d = 0; d < 64; ++d) acc[d] = 0.f;
    float m = -3.0e38f, l = 0.f;
    const float scale = 0.17677669529663687f;  // 32^-0.5

    const float* kg = qkv + E_DIM + rh * D_DIM;
    const float* vg = qkv + 2 * E_DIM + h * 64;
    const int ntiles = rb + 1;

    for (int jt = 0; jt < ntiles; ++jt) {
        const int j0 = jt * 64;
        __syncthreads();
        // stage K: 512 f4, 2 per thread
#pragma unroll
        for (int u = 0; u < 2; ++u) {
            int idx = tid * 2 + u;
            int row = idx >> 3, fi = idx & 7;
            Ks[row * 8 + (fi ^ (row & 7))] =
                *(const float4*)(kg + (size_t)(j0 + row) * 3072 + fi * 4);
        }
        // stage V: 1024 f4, 4 per thread
#pragma unroll
        for (int u = 0; u < 4; ++u) {
            int idx = tid * 4 + u;
            int row = idx >> 4, fi = idx & 15;
            Vs[row * 16 + (fi ^ ((row & 7) << 1))] =
                *(const float4*)(vg + (size_t)(j0 + row) * 3072 + fi * 4);
        }
        __syncthreads();

#pragma unroll 2
        for (int t2 = 0; t2 < 16; ++t2) {
            const int lj = t2 * 4 + sub;
            const int j = j0 + lj;
            if (j <= i) {
                float d0 = 0.f, d1 = 0.f, d2 = 0.f, d3 = 0.f;
                const int kb = lj * 8, msk = lj & 7;
#pragma unroll
                for (int fi = 0; fi < 8; ++fi) {
                    float4 kf = Ks[kb + (fi ^ msk)];
                    d0 = fmaf(q[fi * 4 + 0], kf.x, d0);
                    d1 = fmaf(q[fi * 4 + 1], kf.y, d1);
                    d2 = fmaf(q[fi * 4 + 2], kf.z, d2);
                    d3 = fmaf(q[fi * 4 + 3], kf.w, d3);
                }
                float sc = ((d0 + d1) + (d2 + d3)) * scale;
                if (sc > m) {
                    float corr = __expf(m - sc);
                    l *= corr;
#pragma unroll
                    for (int d = 0; d < 64; ++d) acc[d] *= corr;
                    m = sc;
                }
                float p = __expf(sc - m);
                l += p;
                const int vb = lj * 16, msk2 = (lj & 7) << 1;
#pragma unroll
                for (int fi = 0; fi < 16; ++fi) {
                    float4 vf = Vs[vb + (fi ^ msk2)];
                    acc[fi * 4 + 0] = fmaf(p, vf.x, acc[fi * 4 + 0]);
                    acc[fi * 4 + 1] = fmaf(p, vf.y, acc[fi * 4 + 1]);
                    acc[fi * 4 + 2] = fmaf(p, vf.z, acc[fi * 4 + 2]);
                    acc[fi * 4 + 3] = fmaf(p, vf.w, acc[fi * 4 + 3]);
                }
            }
        }
    }

    // merge the 4 j-split partials (lanes 4r..4r+3, same wave)
    float M2 = fmaxf(m, __shfl_xor(m, 1, 64));
    M2 = fmaxf(M2, __shfl_xor(M2, 2, 64));
    float f = __expf(m - M2);           // 0 for empty partials (m = -3e38)
    float lf = l * f;
    lf += __shfl_xor(lf, 1, 64);
    lf += __shfl_xor(lf, 2, 64);
#pragma unroll
    for (int d = 0; d < 64; ++d) {
        float v = acc[d] * f;
        v += __shfl_xor(v, 1, 64);
        v += __shfl_xor(v, 2, 64);
        acc[d] = v;
    }
    float rl = 1.0f / lf;
    float* op = attn + ((size_t)a * S_LEN + i) * E_DIM + h * 64 + sub * 16;

#define WQ(S) if (sub == S) {                                                   \
        float4 o;                                                               \
        o.x = acc[S*16+ 0]*rl; o.y = acc[S*16+ 1]*rl; o.z = acc[S*16+ 2]*rl; o.w = acc[S*16+ 3]*rl; *(float4*)(op +  0) = o; \
        o.x = acc[S*16+ 4]*rl; o.y = acc[S*16+ 5]*rl; o.z = acc[S*16+ 6]*rl; o.w = acc[S*16+ 7]*rl; *(float4*)(op +  4) = o; \
        o.x = acc[S*16+ 8]*rl; o.y = acc[S*16+ 9]*rl; o.z = acc[S*16+10]*rl; o.w = acc[S*16+11]*rl; *(float4*)(op +  8) = o; \
        o.x = acc[S*16+12]*rl; o.y = acc[S*16+13]*rl; o.z = acc[S*16+14]*rl; o.w = acc[S*16+15]*rl; *(float4*)(op + 12) = o; }
    WQ(0) WQ(1) WQ(2) WQ(3)
#undef WQ
}

// ---------------------------------------------------------------------------
// c = attn1 - lam*attn2 ; rmsnorm(64, eps 1e-8)*ln_w+ln_b ; *(1-LAMBDA_INIT)
// -> bf16 out (next GEMM input). One wave per (s,h).
// ---------------------------------------------------------------------------
__global__ __launch_bounds__(256) void diffnorm_kernel(
    const float* __restrict__ attn, const float* __restrict__ ln_w,
    const float* __restrict__ ln_b, const float* __restrict__ lamp,
    __bf16* __restrict__ out)
{
    int g = blockIdx.x * 4 + (threadIdx.x >> 6);   // 0..32767
    int lane = threadIdx.x & 63;
    int s = g >> 4;
    int h = g & 15;
    float lam = lamp[0];
    const float* p1 = attn + (size_t)s * E_DIM + h * 64;
    const float* p2 = attn + (size_t)(S_LEN + s) * E_DIM + h * 64;
    float c = p1[lane] - lam * p2[lane];
    float sq = c * c;
#pragma unroll
    for (int off = 32; off >= 1; off >>= 1) sq += __shfl_xor(sq, off, 64);
    float ms = sq * (1.0f / 64.0f);
    float r = 1.0f / sqrtf(ms + 1e-8f);
    float o = (c * r * ln_w[lane] + ln_b[lane]) * ONE_MINUS_LAMBDA_INIT;
    out[(size_t)s * E_DIM + h * 64 + lane] = (__bf16)o;
}

// ---------------------------------------------------------------------------
// LayerNorm over E=1024, eps 1e-5; optional bf16 secondary output.
// ---------------------------------------------------------------------------
__global__ __launch_bounds__(256) void ln_kernel(
    const float* __restrict__ in, const float* __restrict__ w,
    const float* __restrict__ b, float* __restrict__ out,
    __bf16* __restrict__ outb)
{
    __shared__ float red[4];
    int row = blockIdx.x;
    int t = threadIdx.x;
    const float* xr = in + (size_t)row * E_DIM + t * 4;
    float4 v = *(const float4*)xr;
    float s = v.x + v.y + v.z + v.w;
#pragma unroll
    for (int off = 32; off >= 1; off >>= 1) s += __shfl_xor(s, off, 64);
    if ((t & 63) == 0) red[t >> 6] = s;
    __syncthreads();
    float mu = (red[0] + red[1] + red[2] + red[3]) * (1.0f / 1024.0f);
    __syncthreads();
    float dx0 = v.x - mu, dx1 = v.y - mu, dx2 = v.z - mu, dx3 = v.w - mu;
    float sq = dx0 * dx0 + dx1 * dx1 + dx2 * dx2 + dx3 * dx3;
#pragma unroll
    for (int off = 32; off >= 1; off >>= 1) sq += __shfl_xor(sq, off, 64);
    if ((t & 63) == 0) red[t >> 6] = sq;
    __syncthreads();
    float var = (red[0] + red[1] + red[2] + red[3]) * (1.0f / 1024.0f);
    float r = 1.0f / sqrtf(var + 1e-5f);
    float4 wv = *(const float4*)(w + t * 4);
    float4 bv = *(const float4*)(b + t * 4);
    float4 o;
    o.x = dx0 * r * wv.x + bv.x;
    o.y = dx1 * r * wv.y + bv.y;
    o.z = dx2 * r * wv.z + bv.z;
    o.w = dx3 * r * wv.w + bv.w;
    *(float4*)(out + (size_t)row * E_DIM + t * 4) = o;
    if (outb) {
        v4bf ob;
        ob[0] = (__bf16)o.x; ob[1] = (__bf16)o.y;
        ob[2] = (__bf16)o.z; ob[3] = (__bf16)o.w;
        *(v4bf*)(outb + (size_t)row * E_DIM + t * 4) = ob;
    }
}

// ---------------------------------------------------------------------------
extern "C" void kernel_launch(void* const* d_in, const int* in_sizes, int n_in,
                              void* d_out, int out_size, void* d_ws, size_t ws_size,
                              hipStream_t stream)
{
    const float* x       = (const float*)d_in[0];
    const float* emb     = (const float*)d_in[1];
    const float* qkv_w   = (const float*)d_in[2];
    const float* out_w   = (const float*)d_in[3];
    const float* sigma_w = (const float*)d_in[4];
    const float* lq1     = (const float*)d_in[5];
    const float* lk1     = (const float*)d_in[6];
    const float* lq2     = (const float*)d_in[7];
    const float* lk2     = (const float*)d_in[8];
    const float* ln_w    = (const float*)d_in[9];
    const float* ln_b    = (const float*)d_in[10];
    const float* ln1_w   = (const float*)d_in[11];
    const float* ln1_b   = (const float*)d_in[12];
    const float* ln2_w   = (const float*)d_in[13];
    const float* ln2_b   = (const float*)d_in[14];
    const float* w1      = (const float*)d_in[15];
    const float* b1      = (const float*)d_in[16];
    const float* w2      = (const float*)d_in[17];
    const float* b2      = (const float*)d_in[18];
    float* out = (float*)d_out;
    char* ws = (char*)d_ws;

    float*  qkv  = (float*)(ws + B_QKV);
    __bf16* g    = (__bf16*)(ws + B_G);
    __bf16* xb   = (__bf16*)(ws + B_XB);
    float*  attn = (float*)(ws + B_ATTN);
    float*  t1   = (float*)(ws + B_T1);
    __bf16* hb   = (__bf16*)(ws + B_HB);
    float*  t2   = (float*)(ws + B_T2);
    __bf16* anrm = (__bf16*)(ws + B_ANRM);
    float*  hbuf = (float*)(ws + B_HBUF);
    __bf16* qwb  = (__bf16*)(ws + B_QWB);
    __bf16* owb  = (__bf16*)(ws + B_OWB);
    __bf16* w1b  = (__bf16*)(ws + B_W1B);
    __bf16* w2b  = (__bf16*)(ws + B_W2B);
    float*  tab  = (float*)(ws + B_TAB);
    float*  sig  = tab + 32768;
    float*  lam  = tab + 32800;

    // 1. tables + sig/lam
    tab_kernel<<<64, 256, 0, stream>>>(tab);
    sig_lam_kernel<<<1, 64, 0, stream>>>(emb, sigma_w, lq1, lk1, lq2, lk2, sig, lam);
    // 2. bf16 conversions for GEMM1
    f2b_kernel<<<1024, 256, 0, stream>>>(x, xb, 2097152);
    f2b_kernel<<<1536, 256, 0, stream>>>(qkv_w, qwb, 3145728);
    // 3. qkv = x @ qkv_w^T   (2048 x 3072 x 1024)
    mgemm_kernel<false, false, false, false><<<dim3(24, 16), 256, 0, stream>>>(
        xb, qwb, qkv, (__bf16*)0, 2048, 3072, 1024, (const float*)0, (const float*)0);
    // 4. RoPE + sigma
    rope_kernel<<<512, 256, 0, stream>>>(qkv, tab, sig);
    // 5. dual causal attention
    attn_kernel<<<1024, 256, 0, stream>>>(qkv, attn);
    // 6. diff + rmsnorm -> bf16
    diffnorm_kernel<<<8192, 256, 0, stream>>>(attn, ln_w, ln_b, lam, anrm);
    // 7. out_w -> bf16 (qkv region now dead)
    f2b_kernel<<<512, 256, 0, stream>>>(out_w, owb, 1048576);
    // 8. t1 = anrm @ out_w^T + x   (2048 x 1024 x 1024)
    mgemm_kernel<false, false, true, false><<<dim3(8, 16), 256, 0, stream>>>(
        anrm, owb, t1, (__bf16*)0, 2048, 1024, 1024, (const float*)0, x);
    // 9. h = layernorm(t1)  (fp32 + bf16)
    ln_kernel<<<2048, 256, 0, stream>>>(t1, ln1_w, ln1_b, hbuf, hb);
    // 10. w1 -> bf16
    f2b_kernel<<<2048, 256, 0, stream>>>(w1, w1b, 4194304);
    // 11. g = silu(h @ w1^T + b1) -> bf16   (2048 x 4096 x 1024)
    mgemm_kernel<true, true, false, true><<<dim3(32, 16), 256, 0, stream>>>(
        hb, w1b, (float*)0, g, 2048, 4096, 1024, b1, (const float*)0);
    // 12. w2 -> bf16
    f2b_kernel<<<2048, 256, 0, stream>>>(w2, w2b, 4194304);
    // 13. t2 = g @ w2^T + b2 + h   (2048 x 1024 x 4096)
    mgemm_kernel<true, false, true, false><<<dim3(8, 16), 256, 0, stream>>>(
        g, w2b, t2, (__bf16*)0, 2048, 1024, 4096, b2, hbuf);
    // 14. out = layernorm(t2)
    ln_kernel<<<2048, 256, 0, stream>>>(t2, ln2_w, ln2_b, out, (__bf16*)0);
}

// Round 7
// 478.124 us; speedup vs baseline: 7.6912x; 1.6355x over previous
//
#include <hip/hip_runtime.h>
#include <hip/hip_bf16.h>
#include <math.h>

// ---------------------------------------------------------------------------
// DiffTransformer block. B=1, S=2048, E=1024, H=16, D=32, SIG=256.
// Round 7 (= round 6 design; round 6 hit infra GPU timeout, never ran):
// MFMA flash attention (replaces VALU attention, was 484us/62%).
// GEMMs: bf16 MFMA m97 structure (unchanged from round 5).
// All GEMMs: C[M,N] = A[M,K] @ B[N,K]^T (weights row-major [N,K]).
// ---------------------------------------------------------------------------

#define S_LEN 2048
#define E_DIM 1024
#define H_NUM 16
#define D_DIM 32
#define SIG_DIM 256

#define LAMBDA_INIT 0.3555090675909693f
#define ONE_MINUS_LAMBDA_INIT 0.6444909324090307f

typedef __bf16 v8bf __attribute__((ext_vector_type(8)));
typedef __bf16 v4bf __attribute__((ext_vector_type(4)));
typedef float f32x4 __attribute__((ext_vector_type(4)));
static_assert(sizeof(v8bf) == 16, "v8bf must be 16B");

// ---- workspace layout (BYTE offsets) --------------------------------------
#define B_QKV   0
#define B_G     8388608
#define B_XB    25165824
#define B_ATTN  25165824
#define B_T1    25165824
#define B_HB    33554432
#define B_T2    33554432
#define B_ANRM  41943040
#define B_HBUF  41943040
#define B_QWB   50331648
#define B_OWB   0
#define B_W1B   0
#define B_W2B   0
#define B_TAB   56623104

// ---------------------------------------------------------------------------
__global__ __launch_bounds__(256) void tab_kernel(float* __restrict__ tab) {
    int t = blockIdx.x * 256 + threadIdx.x;     // 0..16383
    int s = t >> 3;
    int pi = t & 7;
    double inv = pow(10000.0, -(double)pi / 8.0);
    double ph = (double)s * inv;
    tab[t]         = (float)cos(ph);
    tab[16384 + t] = (float)sin(ph);
}

__global__ __launch_bounds__(64) void sig_lam_kernel(
    const float* __restrict__ emb, const float* __restrict__ sigma_w,
    const float* __restrict__ lq1, const float* __restrict__ lk1,
    const float* __restrict__ lq2, const float* __restrict__ lk2,
    float* __restrict__ sig, float* __restrict__ lam)
{
    int t = threadIdx.x;
    if (t < 32) {
        float acc = 0.f;
        for (int j = 0; j < SIG_DIM; ++j)
            acc = fmaf(emb[j], sigma_w[t * SIG_DIM + j], acc);
        sig[t] = acc;
    } else if (t == 32) {
        float s1 = 0.f, s2 = 0.f;
        for (int d = 0; d < D_DIM; ++d) {
            s1 = fmaf(lq1[d], lk1[d], s1);
            s2 = fmaf(lq2[d], lk2[d], s2);
        }
        lam[0] = expf(s1) - expf(s2) + LAMBDA_INIT;
    }
}

// ---------------------------------------------------------------------------
__global__ __launch_bounds__(256) void f2b_kernel(
    const float* __restrict__ in, __bf16* __restrict__ out, int n)
{
    int base = (blockIdx.x * 256 + threadIdx.x) * 8;
    if (base >= n) return;
    float4 v0 = *(const float4*)(in + base);
    float4 v1 = *(const float4*)(in + base + 4);
    v8bf o;
    o[0] = (__bf16)v0.x; o[1] = (__bf16)v0.y; o[2] = (__bf16)v0.z; o[3] = (__bf16)v0.w;
    o[4] = (__bf16)v1.x; o[5] = (__bf16)v1.y; o[6] = (__bf16)v1.z; o[7] = (__bf16)v1.w;
    *(v8bf*)(out + base) = o;
}

// ---------------------------------------------------------------------------
// bf16 MFMA GEMM (m97 structure) — unchanged from round 5.
// ---------------------------------------------------------------------------
__device__ __forceinline__ void gload_lds16(const __bf16* g, __bf16* l) {
    __builtin_amdgcn_global_load_lds(
        (const __attribute__((address_space(1))) unsigned int*)g,
        (__attribute__((address_space(3))) unsigned int*)l, 16, 0, 0);
}

template<bool BIAS, bool SILU, bool RES, bool OBF16>
__global__ __launch_bounds__(256) void mgemm_kernel(
    const __bf16* __restrict__ A, const __bf16* __restrict__ B,
    float* __restrict__ C, __bf16* __restrict__ Cb,
    int M, int N, int K,
    const float* __restrict__ bias, const float* __restrict__ res)
{
    __shared__ __bf16 As[128][32];
    __shared__ __bf16 Bs[128][32];

    const int tid  = threadIdx.x;
    const int wid  = tid >> 6;
    const int lane = tid & 63;
    const int m0 = blockIdx.y * 128;
    const int n0 = blockIdx.x * 128;
    const int wr = (wid >> 1) * 64;
    const int wc = (wid & 1) * 64;
    const int lrow = lane & 15;
    const int kg   = lane >> 4;        // 0..3

    f32x4 acc[4][4];
#pragma unroll
    for (int mi = 0; mi < 4; ++mi)
#pragma unroll
        for (int ni = 0; ni < 4; ++ni) acc[mi][ni] = (f32x4){0.f, 0.f, 0.f, 0.f};

    const int srow = lane >> 2;        // 0..15
    const int sfi  = lane & 3;
    const __bf16* Ap0 = A + (size_t)(m0 + wid * 16 + srow) * K + sfi * 8;
    const __bf16* Ap1 = Ap0 + (size_t)64 * K;
    const __bf16* Bp0 = B + (size_t)(n0 + wid * 16 + srow) * K + sfi * 8;
    const __bf16* Bp1 = Bp0 + (size_t)64 * K;
    __bf16* Al0 = &As[wid * 16][0];
    __bf16* Al1 = &As[64 + wid * 16][0];
    __bf16* Bl0 = &Bs[wid * 16][0];
    __bf16* Bl1 = &Bs[64 + wid * 16][0];

    for (int k0 = 0; k0 < K; k0 += 32) {
        __syncthreads();
        gload_lds16(Ap0 + k0, Al0);
        gload_lds16(Ap1 + k0, Al1);
        gload_lds16(Bp0 + k0, Bl0);
        gload_lds16(Bp1 + k0, Bl1);
        __syncthreads();

        v8bf a[4], b[4];
#pragma unroll
        for (int mi = 0; mi < 4; ++mi)
            a[mi] = *(const v8bf*)&As[wr + mi * 16 + lrow][kg * 8];
#pragma unroll
        for (int ni = 0; ni < 4; ++ni)
            b[ni] = *(const v8bf*)&Bs[wc + ni * 16 + lrow][kg * 8];
#pragma unroll
        for (int mi = 0; mi < 4; ++mi)
#pragma unroll
            for (int ni = 0; ni < 4; ++ni)
                acc[mi][ni] = __builtin_amdgcn_mfma_f32_16x16x32_bf16(
                    a[mi], b[ni], acc[mi][ni], 0, 0, 0);
    }

    const int crow = (lane >> 4) * 4;
    const int ccol = lane & 15;
#pragma unroll
    for (int mi = 0; mi < 4; ++mi) {
#pragma unroll
        for (int ni = 0; ni < 4; ++ni) {
            const int col = n0 + wc + ni * 16 + ccol;
            float bv = 0.f;
            if (BIAS) bv = bias[col];
#pragma unroll
            for (int j = 0; j < 4; ++j) {
                const int row = m0 + wr + mi * 16 + crow + j;
                float v = acc[mi][ni][j] + bv;
                if (SILU) v = v / (1.f + expf(-v));
                if (RES) v += res[(size_t)row * N + col];
                if (OBF16) Cb[(size_t)row * N + col] = (__bf16)v;
                else       C[(size_t)row * N + col] = v;
            }
        }
    }
}

// ---------------------------------------------------------------------------
// RoPE in-place on q,k of qkv + sig add to odd rope-heads (unchanged).
// ---------------------------------------------------------------------------
__global__ __launch_bounds__(256) void rope_kernel(
    float* __restrict__ qkv, const float* __restrict__ tab,
    const float* __restrict__ sig)
{
    int t = blockIdx.x * 256 + threadIdx.x;   // 0..131071
    int s    = t >> 6;
    int sub  = t & 63;
    int part = sub >> 5;    // 0=q, 1=k
    int rh   = sub & 31;
    float* p = qkv + (size_t)s * 3072 + part * E_DIM + rh * D_DIM;
    const float* ct = tab + s * 8;
    const float* st = tab + 16384 + s * 8;

    float v[16];
#pragma unroll
    for (int i = 0; i < 4; ++i) *(float4*)(v + i * 4) = *(const float4*)(p + i * 4);
    float o[16];
#pragma unroll
    for (int pi = 0; pi < 8; ++pi) {
        float c = ct[pi], sn = st[pi];
        float x1 = v[2 * pi], x2 = v[2 * pi + 1];
        o[2 * pi]     = x1 * c - x2 * sn;
        o[2 * pi + 1] = x2 * c + x1 * sn;
    }
    if (rh & 1) {
#pragma unroll
        for (int i = 0; i < 16; ++i) o[i] += sig[i];
        float u[16];
#pragma unroll
        for (int i = 0; i < 4; ++i) *(float4*)(u + i * 4) = *(const float4*)(p + 16 + i * 4);
#pragma unroll
        for (int i = 0; i < 16; ++i) u[i] += sig[16 + i];
#pragma unroll
        for (int i = 0; i < 4; ++i) *(float4*)(p + 16 + i * 4) = *(const float4*)(u + i * 4);
    }
#pragma unroll
    for (int i = 0; i < 4; ++i) *(float4*)(p + i * 4) = *(const float4*)(o + i * 4);
}

// ---------------------------------------------------------------------------
// MFMA flash attention.
// Block = 256 thr (4 waves) = one (a,h), one 64-row q-tile. Wave wq: 16 rows.
// Per 64-key KV tile: K -> bf16 LDS [64key][32d] (xor-swz 16B slots),
// V -> bf16 LDS transposed [64d][64k] (xor-swz), QK^T = 4 MFMA 16x16x32,
// online softmax in C-layout, P -> bf16 -> per-wave LDS (transpose to A-frag),
// PV = 8 MFMA. Diagonal tile masked. Scale folded into Q bf16 conversion.
// C/D layout: col=lane&15, row=(lane>>4)*4+reg (verified m89/m91).
// A/B frag: idx=lane&15, k=(lane>>4)*8+e.
// ---------------------------------------------------------------------------
__global__ __launch_bounds__(256, 2) void fattn_kernel(
    const float* __restrict__ qkv, float* __restrict__ attn)
{
    __shared__ __bf16 Ks[2048];    // [64key][32d], 16B slot s=key*4+(d>>3), stored s^((key>>1)&3)
    __shared__ __bf16 Vt[4096];    // [64d][64k], elem (d*64+k)^((d&7)<<3)
    __shared__ __bf16 Pl[4096];    // 4 waves x [16q][64k], elem (q*64+k)^((q&7)<<3)

    const int bid = blockIdx.x;          // 0..1023
    const int rb = bid & 31;             // q-tile (interleaved for balance)
    const int ah = bid >> 5;
    const int h = ah >> 1;
    const int a = ah & 1;
    const int rh = 2 * h + a;
    const int i0 = rb * 64;
    const int tid = threadIdx.x;
    const int wq = tid >> 6;
    const int lane = tid & 63;
    const int c = lane & 15;
    const int g = lane >> 4;

    // Q fragment: rows i0+wq*16+c, d = g*8..+8, scale folded in.
    const float scale = 0.17677669529663687f;  // 32^-0.5
    const float* qp = qkv + (size_t)(i0 + wq * 16 + c) * 3072 + rh * 32 + g * 8;
    float4 q0 = *(const float4*)qp;
    float4 q1 = *(const float4*)(qp + 4);
    v8bf qf;
    qf[0] = (__bf16)(q0.x * scale); qf[1] = (__bf16)(q0.y * scale);
    qf[2] = (__bf16)(q0.z * scale); qf[3] = (__bf16)(q0.w * scale);
    qf[4] = (__bf16)(q1.x * scale); qf[5] = (__bf16)(q1.y * scale);
    qf[6] = (__bf16)(q1.z * scale); qf[7] = (__bf16)(q1.w * scale);

    f32x4 o_acc[4];
#pragma unroll
    for (int nj = 0; nj < 4; ++nj) o_acc[nj] = (f32x4){0.f, 0.f, 0.f, 0.f};
    float m_run[4] = {-3.0e38f, -3.0e38f, -3.0e38f, -3.0e38f};
    float l_run[4] = {0.f, 0.f, 0.f, 0.f};

    // staging assignments
    const int sk_key = tid >> 2, sk_ds = tid & 3;     // K: row, 8-d slice
    const int sk_slot = (((sk_key * 4 + sk_ds) ^ ((sk_key >> 1) & 3)) * 8);
    const int sv_k = tid >> 2, sv_dg = tid & 3;       // V: row, 16-d group
    const int pbase = wq * 1024;

    for (int jt = 0; jt <= rb; ++jt) {
        const int j0 = jt * 64;
        __syncthreads();
        {   // stage K tile -> bf16 swizzled
            const float* src = qkv + (size_t)(j0 + sk_key) * 3072 + E_DIM + rh * 32 + sk_ds * 8;
            float4 a0 = *(const float4*)src;
            float4 a1 = *(const float4*)(src + 4);
            v8bf kb;
            kb[0] = (__bf16)a0.x; kb[1] = (__bf16)a0.y; kb[2] = (__bf16)a0.z; kb[3] = (__bf16)a0.w;
            kb[4] = (__bf16)a1.x; kb[5] = (__bf16)a1.y; kb[6] = (__bf16)a1.z; kb[7] = (__bf16)a1.w;
            *(v8bf*)&Ks[sk_slot] = kb;
        }
        {   // stage V tile transposed -> bf16 swizzled (coalesced loads, b16 scatter)
            const float* src = qkv + (size_t)(j0 + sv_k) * 3072 + 2 * E_DIM + h * 64 + sv_dg * 16;
            float4 v0 = *(const float4*)src;
            float4 v1 = *(const float4*)(src + 4);
            float4 v2 = *(const float4*)(src + 8);
            float4 v3 = *(const float4*)(src + 12);
            float vv[16] = {v0.x, v0.y, v0.z, v0.w, v1.x, v1.y, v1.z, v1.w,
                            v2.x, v2.y, v2.z, v2.w, v3.x, v3.y, v3.z, v3.w};
#pragma unroll
            for (int e = 0; e < 16; ++e) {
                int d = sv_dg * 16 + e;
                Vt[(d * 64 + sv_k) ^ ((d & 7) << 3)] = (__bf16)vv[e];
            }
        }
        __syncthreads();

        // QK^T: 4 MFMA over key groups
        f32x4 s[4];
#pragma unroll
        for (int ni = 0; ni < 4; ++ni) {
            int slot = ((((16 * ni + c) * 4 + g) ^ ((c >> 1) & 3)) * 8);
            v8bf kf = *(const v8bf*)&Ks[slot];
            s[ni] = __builtin_amdgcn_mfma_f32_16x16x32_bf16(
                qf, kf, (f32x4){0.f, 0.f, 0.f, 0.f}, 0, 0, 0);
        }
        // diagonal-tile causal mask: key_local(16ni+c) > q_local(wq*16+4g+r)
        if (jt == rb) {
#pragma unroll
            for (int ni = 0; ni < 4; ++ni)
#pragma unroll
                for (int r = 0; r < 4; ++r)
                    if (16 * ni + c > wq * 16 + 4 * g + r) s[ni][r] = -3.0e38f;
        }

        // online softmax (per reg r = one query row; 16 c-lanes share a row)
        float p[4][4];
#pragma unroll
        for (int r = 0; r < 4; ++r) {
            float t = fmaxf(fmaxf(s[0][r], s[1][r]), fmaxf(s[2][r], s[3][r]));
            t = fmaxf(t, __shfl_xor(t, 1, 64));
            t = fmaxf(t, __shfl_xor(t, 2, 64));
            t = fmaxf(t, __shfl_xor(t, 4, 64));
            t = fmaxf(t, __shfl_xor(t, 8, 64));
            float mnew = fmaxf(m_run[r], t);
            float corr = __expf(m_run[r] - mnew);
            m_run[r] = mnew;
            l_run[r] *= corr;
#pragma unroll
            for (int nj = 0; nj < 4; ++nj) o_acc[nj][r] *= corr;
#pragma unroll
            for (int ni = 0; ni < 4; ++ni) {
                float pp = __expf(s[ni][r] - mnew);
                p[ni][r] = pp;
                l_run[r] += pp;
            }
        }

        // P -> bf16 -> per-wave LDS (C-layout -> A-frag transpose)
#pragma unroll
        for (int ni = 0; ni < 4; ++ni)
#pragma unroll
            for (int r = 0; r < 4; ++r) {
                int q = 4 * g + r;
                Pl[pbase + ((q * 64 + 16 * ni + c) ^ ((q & 7) << 3))] = (__bf16)p[ni][r];
            }
        asm volatile("s_waitcnt lgkmcnt(0)" ::: "memory");
        __builtin_amdgcn_sched_barrier(0);

        // PV: O[16q x 64d] += P[16 x 64] @ V[64 x 64]
        v8bf pa[2];
#pragma unroll
        for (int kj = 0; kj < 2; ++kj)
            pa[kj] = *(const v8bf*)&Pl[pbase + ((c * 64 + kj * 32 + g * 8) ^ ((c & 7) << 3))];
#pragma unroll
        for (int nj = 0; nj < 4; ++nj) {
            int d = 16 * nj + c;
#pragma unroll
            for (int kj = 0; kj < 2; ++kj) {
                v8bf vb = *(const v8bf*)&Vt[(d * 64 + kj * 32 + g * 8) ^ ((c & 7) << 3)];
                o_acc[nj] = __builtin_amdgcn_mfma_f32_16x16x32_bf16(
                    pa[kj], vb, o_acc[nj], 0, 0, 0);
            }
        }
    }

    // epilogue: row-sum of l, normalize, store f32
#pragma unroll
    for (int r = 0; r < 4; ++r) {
        float lt = l_run[r];
        lt += __shfl_xor(lt, 1, 64);
        lt += __shfl_xor(lt, 2, 64);
        lt += __shfl_xor(lt, 4, 64);
        lt += __shfl_xor(lt, 8, 64);
        l_run[r] = 1.0f / lt;
    }
#pragma unroll
    for (int nj = 0; nj < 4; ++nj)
#pragma unroll
        for (int r = 0; r < 4; ++r) {
            int qg = i0 + wq * 16 + 4 * g + r;
            attn[((size_t)a * S_LEN + qg) * E_DIM + h * 64 + 16 * nj + c] =
                o_acc[nj][r] * l_run[r];
        }
}

// ---------------------------------------------------------------------------
// diff + rmsnorm -> bf16 (unchanged).
// ---------------------------------------------------------------------------
__global__ __launch_bounds__(256) void diffnorm_kernel(
    const float* __restrict__ attn, const float* __restrict__ ln_w,
    const float* __restrict__ ln_b, const float* __restrict__ lamp,
    __bf16* __restrict__ out)
{
    int g = blockIdx.x * 4 + (threadIdx.x >> 6);   // 0..32767
    int lane = threadIdx.x & 63;
    int s = g >> 4;
    int h = g & 15;
    float lam = lamp[0];
    const float* p1 = attn + (size_t)s * E_DIM + h * 64;
    const float* p2 = attn + (size_t)(S_LEN + s) * E_DIM + h * 64;
    float c = p1[lane] - lam * p2[lane];
    float sq = c * c;
#pragma unroll
    for (int off = 32; off >= 1; off >>= 1) sq += __shfl_xor(sq, off, 64);
    float ms = sq * (1.0f / 64.0f);
    float r = 1.0f / sqrtf(ms + 1e-8f);
    float o = (c * r * ln_w[lane] + ln_b[lane]) * ONE_MINUS_LAMBDA_INIT;
    out[(size_t)s * E_DIM + h * 64 + lane] = (__bf16)o;
}

// ---------------------------------------------------------------------------
// LayerNorm over E=1024 (unchanged).
// ---------------------------------------------------------------------------
__global__ __launch_bounds__(256) void ln_kernel(
    const float* __restrict__ in, const float* __restrict__ w,
    const float* __restrict__ b, float* __restrict__ out,
    __bf16* __restrict__ outb)
{
    __shared__ float red[4];
    int row = blockIdx.x;
    int t = threadIdx.x;
    const float* xr = in + (size_t)row * E_DIM + t * 4;
    float4 v = *(const float4*)xr;
    float s = v.x + v.y + v.z + v.w;
#pragma unroll
    for (int off = 32; off >= 1; off >>= 1) s += __shfl_xor(s, off, 64);
    if ((t & 63) == 0) red[t >> 6] = s;
    __syncthreads();
    float mu = (red[0] + red[1] + red[2] + red[3]) * (1.0f / 1024.0f);
    __syncthreads();
    float dx0 = v.x - mu, dx1 = v.y - mu, dx2 = v.z - mu, dx3 = v.w - mu;
    float sq = dx0 * dx0 + dx1 * dx1 + dx2 * dx2 + dx3 * dx3;
#pragma unroll
    for (int off = 32; off >= 1; off >>= 1) sq += __shfl_xor(sq, off, 64);
    if ((t & 63) == 0) red[t >> 6] = sq;
    __syncthreads();
    float var = (red[0] + red[1] + red[2] + red[3]) * (1.0f / 1024.0f);
    float r = 1.0f / sqrtf(var + 1e-5f);
    float4 wv = *(const float4*)(w + t * 4);
    float4 bv = *(const float4*)(b + t * 4);
    float4 o;
    o.x = dx0 * r * wv.x + bv.x;
    o.y = dx1 * r * wv.y + bv.y;
    o.z = dx2 * r * wv.z + bv.z;
    o.w = dx3 * r * wv.w + bv.w;
    *(float4*)(out + (size_t)row * E_DIM + t * 4) = o;
    if (outb) {
        v4bf ob;
        ob[0] = (__bf16)o.x; ob[1] = (__bf16)o.y;
        ob[2] = (__bf16)o.z; ob[3] = (__bf16)o.w;
        *(v4bf*)(outb + (size_t)row * E_DIM + t * 4) = ob;
    }
}

// ---------------------------------------------------------------------------
extern "C" void kernel_launch(void* const* d_in, const int* in_sizes, int n_in,
                              void* d_out, int out_size, void* d_ws, size_t ws_size,
                              hipStream_t stream)
{
    const float* x       = (const float*)d_in[0];
    const float* emb     = (const float*)d_in[1];
    const float* qkv_w   = (const float*)d_in[2];
    const float* out_w   = (const float*)d_in[3];
    const float* sigma_w = (const float*)d_in[4];
    const float* lq1     = (const float*)d_in[5];
    const float* lk1     = (const float*)d_in[6];
    const float* lq2     = (const float*)d_in[7];
    const float* lk2     = (const float*)d_in[8];
    const float* ln_w    = (const float*)d_in[9];
    const float* ln_b    = (const float*)d_in[10];
    const float* ln1_w   = (const float*)d_in[11];
    const float* ln1_b   = (const float*)d_in[12];
    const float* ln2_w   = (const float*)d_in[13];
    const float* ln2_b   = (const float*)d_in[14];
    const float* w1      = (const float*)d_in[15];
    const float* b1      = (const float*)d_in[16];
    const float* w2      = (const float*)d_in[17];
    const float* b2      = (const float*)d_in[18];
    float* out = (float*)d_out;
    char* ws = (char*)d_ws;

    float*  qkv  = (float*)(ws + B_QKV);
    __bf16* g    = (__bf16*)(ws + B_G);
    __bf16* xb   = (__bf16*)(ws + B_XB);
    float*  attn = (float*)(ws + B_ATTN);
    float*  t1   = (float*)(ws + B_T1);
    __bf16* hb   = (__bf16*)(ws + B_HB);
    float*  t2   = (float*)(ws + B_T2);
    __bf16* anrm = (__bf16*)(ws + B_ANRM);
    float*  hbuf = (float*)(ws + B_HBUF);
    __bf16* qwb  = (__bf16*)(ws + B_QWB);
    __bf16* owb  = (__bf16*)(ws + B_OWB);
    __bf16* w1b  = (__bf16*)(ws + B_W1B);
    __bf16* w2b  = (__bf16*)(ws + B_W2B);
    float*  tab  = (float*)(ws + B_TAB);
    float*  sig  = tab + 32768;
    float*  lam  = tab + 32800;

    // 1. tables + sig/lam
    tab_kernel<<<64, 256, 0, stream>>>(tab);
    sig_lam_kernel<<<1, 64, 0, stream>>>(emb, sigma_w, lq1, lk1, lq2, lk2, sig, lam);
    // 2. bf16 conversions for GEMM1
    f2b_kernel<<<1024, 256, 0, stream>>>(x, xb, 2097152);
    f2b_kernel<<<1536, 256, 0, stream>>>(qkv_w, qwb, 3145728);
    // 3. qkv = x @ qkv_w^T   (2048 x 3072 x 1024)
    mgemm_kernel<false, false, false, false><<<dim3(24, 16), 256, 0, stream>>>(
        xb, qwb, qkv, (__bf16*)0, 2048, 3072, 1024, (const float*)0, (const float*)0);
    // 4. RoPE + sigma
    rope_kernel<<<512, 256, 0, stream>>>(qkv, tab, sig);
    // 5. dual causal attention (MFMA flash)
    fattn_kernel<<<1024, 256, 0, stream>>>(qkv, attn);
    // 6. diff + rmsnorm -> bf16
    diffnorm_kernel<<<8192, 256, 0, stream>>>(attn, ln_w, ln_b, lam, anrm);
    // 7. out_w -> bf16 (qkv region now dead)
    f2b_kernel<<<512, 256, 0, stream>>>(out_w, owb, 1048576);
    // 8. t1 = anrm @ out_w^T + x   (2048 x 1024 x 1024)
    mgemm_kernel<false, false, true, false><<<dim3(8, 16), 256, 0, stream>>>(
        anrm, owb, t1, (__bf16*)0, 2048, 1024, 1024, (const float*)0, x);
    // 9. h = layernorm(t1)  (fp32 + bf16)
    ln_kernel<<<2048, 256, 0, stream>>>(t1, ln1_w, ln1_b, hbuf, hb);
    // 10. w1 -> bf16
    f2b_kernel<<<2048, 256, 0, stream>>>(w1, w1b, 4194304);
    // 11. g = silu(h @ w1^T + b1) -> bf16   (2048 x 4096 x 1024)
    mgemm_kernel<true, true, false, true><<<dim3(32, 16), 256, 0, stream>>>(
        hb, w1b, (float*)0, g, 2048, 4096, 1024, b1, (const float*)0);
    // 12. w2 -> bf16
    f2b_kernel<<<2048, 256, 0, stream>>>(w2, w2b, 4194304);
    // 13. t2 = g @ w2^T + b2 + h   (2048 x 1024 x 4096)
    mgemm_kernel<true, false, true, false><<<dim3(8, 16), 256, 0, stream>>>(
        g, w2b, t2, (__bf16*)0, 2048, 1024, 4096, b2, hbuf);
    // 14. out = layernorm(t2)
    ln_kernel<<<2048, 256, 0, stream>>>(t2, ln2_w, ln2_b, out, (__bf16*)0);
}

// Round 10
// 438.132 us; speedup vs baseline: 8.3932x; 1.0913x over previous
//
#include <hip/hip_runtime.h>
#include <hip/hip_bf16.h>
#include <math.h>

// ---------------------------------------------------------------------------
// DiffTransformer block. B=1, S=2048, E=1024, H=16, D=32, SIG=256.
// Round 10 (= round 8 design; rounds 8-9 hit infra GPU timeouts, never ran):
// fattn v2 — T14 async staging + LDS double-buffer (1 barrier/tile)
// + XCD-clustered LPT dispatch. (fattn v1: 140us, 72% stall, MfmaUtil 3.6%.)
// GEMMs: bf16 MFMA m97 structure (unchanged).
// All GEMMs: C[M,N] = A[M,K] @ B[N,K]^T (weights row-major [N,K]).
// ---------------------------------------------------------------------------

#define S_LEN 2048
#define E_DIM 1024
#define H_NUM 16
#define D_DIM 32
#define SIG_DIM 256

#define LAMBDA_INIT 0.3555090675909693f
#define ONE_MINUS_LAMBDA_INIT 0.6444909324090307f

typedef __bf16 v8bf __attribute__((ext_vector_type(8)));
typedef __bf16 v4bf __attribute__((ext_vector_type(4)));
typedef float f32x4 __attribute__((ext_vector_type(4)));
static_assert(sizeof(v8bf) == 16, "v8bf must be 16B");

// ---- workspace layout (BYTE offsets) --------------------------------------
#define B_QKV   0
#define B_G     8388608
#define B_XB    25165824
#define B_ATTN  25165824
#define B_T1    25165824
#define B_HB    33554432
#define B_T2    33554432
#define B_ANRM  41943040
#define B_HBUF  41943040
#define B_QWB   50331648
#define B_OWB   0
#define B_W1B   0
#define B_W2B   0
#define B_TAB   56623104

// ---------------------------------------------------------------------------
__global__ __launch_bounds__(256) void tab_kernel(float* __restrict__ tab) {
    int t = blockIdx.x * 256 + threadIdx.x;     // 0..16383
    int s = t >> 3;
    int pi = t & 7;
    double inv = pow(10000.0, -(double)pi / 8.0);
    double ph = (double)s * inv;
    tab[t]         = (float)cos(ph);
    tab[16384 + t] = (float)sin(ph);
}

__global__ __launch_bounds__(64) void sig_lam_kernel(
    const float* __restrict__ emb, const float* __restrict__ sigma_w,
    const float* __restrict__ lq1, const float* __restrict__ lk1,
    const float* __restrict__ lq2, const float* __restrict__ lk2,
    float* __restrict__ sig, float* __restrict__ lam)
{
    int t = threadIdx.x;
    if (t < 32) {
        float acc = 0.f;
        for (int j = 0; j < SIG_DIM; ++j)
            acc = fmaf(emb[j], sigma_w[t * SIG_DIM + j], acc);
        sig[t] = acc;
    } else if (t == 32) {
        float s1 = 0.f, s2 = 0.f;
        for (int d = 0; d < D_DIM; ++d) {
            s1 = fmaf(lq1[d], lk1[d], s1);
            s2 = fmaf(lq2[d], lk2[d], s2);
        }
        lam[0] = expf(s1) - expf(s2) + LAMBDA_INIT;
    }
}

// ---------------------------------------------------------------------------
__global__ __launch_bounds__(256) void f2b_kernel(
    const float* __restrict__ in, __bf16* __restrict__ out, int n)
{
    int base = (blockIdx.x * 256 + threadIdx.x) * 8;
    if (base >= n) return;
    float4 v0 = *(const float4*)(in + base);
    float4 v1 = *(const float4*)(in + base + 4);
    v8bf o;
    o[0] = (__bf16)v0.x; o[1] = (__bf16)v0.y; o[2] = (__bf16)v0.z; o[3] = (__bf16)v0.w;
    o[4] = (__bf16)v1.x; o[5] = (__bf16)v1.y; o[6] = (__bf16)v1.z; o[7] = (__bf16)v1.w;
    *(v8bf*)(out + base) = o;
}

// ---------------------------------------------------------------------------
// bf16 MFMA GEMM (m97 structure) — unchanged.
// ---------------------------------------------------------------------------
__device__ __forceinline__ void gload_lds16(const __bf16* g, __bf16* l) {
    __builtin_amdgcn_global_load_lds(
        (const __attribute__((address_space(1))) unsigned int*)g,
        (__attribute__((address_space(3))) unsigned int*)l, 16, 0, 0);
}

template<bool BIAS, bool SILU, bool RES, bool OBF16>
__global__ __launch_bounds__(256) void mgemm_kernel(
    const __bf16* __restrict__ A, const __bf16* __restrict__ B,
    float* __restrict__ C, __bf16* __restrict__ Cb,
    int M, int N, int K,
    const float* __restrict__ bias, const float* __restrict__ res)
{
    __shared__ __bf16 As[128][32];
    __shared__ __bf16 Bs[128][32];

    const int tid  = threadIdx.x;
    const int wid  = tid >> 6;
    const int lane = tid & 63;
    const int m0 = blockIdx.y * 128;
    const int n0 = blockIdx.x * 128;
    const int wr = (wid >> 1) * 64;
    const int wc = (wid & 1) * 64;
    const int lrow = lane & 15;
    const int kg   = lane >> 4;        // 0..3

    f32x4 acc[4][4];
#pragma unroll
    for (int mi = 0; mi < 4; ++mi)
#pragma unroll
        for (int ni = 0; ni < 4; ++ni) acc[mi][ni] = (f32x4){0.f, 0.f, 0.f, 0.f};

    const int srow = lane >> 2;        // 0..15
    const int sfi  = lane & 3;
    const __bf16* Ap0 = A + (size_t)(m0 + wid * 16 + srow) * K + sfi * 8;
    const __bf16* Ap1 = Ap0 + (size_t)64 * K;
    const __bf16* Bp0 = B + (size_t)(n0 + wid * 16 + srow) * K + sfi * 8;
    const __bf16* Bp1 = Bp0 + (size_t)64 * K;
    __bf16* Al0 = &As[wid * 16][0];
    __bf16* Al1 = &As[64 + wid * 16][0];
    __bf16* Bl0 = &Bs[wid * 16][0];
    __bf16* Bl1 = &Bs[64 + wid * 16][0];

    for (int k0 = 0; k0 < K; k0 += 32) {
        __syncthreads();
        gload_lds16(Ap0 + k0, Al0);
        gload_lds16(Ap1 + k0, Al1);
        gload_lds16(Bp0 + k0, Bl0);
        gload_lds16(Bp1 + k0, Bl1);
        __syncthreads();

        v8bf a[4], b[4];
#pragma unroll
        for (int mi = 0; mi < 4; ++mi)
            a[mi] = *(const v8bf*)&As[wr + mi * 16 + lrow][kg * 8];
#pragma unroll
        for (int ni = 0; ni < 4; ++ni)
            b[ni] = *(const v8bf*)&Bs[wc + ni * 16 + lrow][kg * 8];
#pragma unroll
        for (int mi = 0; mi < 4; ++mi)
#pragma unroll
            for (int ni = 0; ni < 4; ++ni)
                acc[mi][ni] = __builtin_amdgcn_mfma_f32_16x16x32_bf16(
                    a[mi], b[ni], acc[mi][ni], 0, 0, 0);
    }

    const int crow = (lane >> 4) * 4;
    const int ccol = lane & 15;
#pragma unroll
    for (int mi = 0; mi < 4; ++mi) {
#pragma unroll
        for (int ni = 0; ni < 4; ++ni) {
            const int col = n0 + wc + ni * 16 + ccol;
            float bv = 0.f;
            if (BIAS) bv = bias[col];
#pragma unroll
            for (int j = 0; j < 4; ++j) {
                const int row = m0 + wr + mi * 16 + crow + j;
                float v = acc[mi][ni][j] + bv;
                if (SILU) v = v / (1.f + expf(-v));
                if (RES) v += res[(size_t)row * N + col];
                if (OBF16) Cb[(size_t)row * N + col] = (__bf16)v;
                else       C[(size_t)row * N + col] = v;
            }
        }
    }
}

// ---------------------------------------------------------------------------
// RoPE in-place on q,k of qkv + sig add to odd rope-heads (unchanged).
// ---------------------------------------------------------------------------
__global__ __launch_bounds__(256) void rope_kernel(
    float* __restrict__ qkv, const float* __restrict__ tab,
    const float* __restrict__ sig)
{
    int t = blockIdx.x * 256 + threadIdx.x;   // 0..131071
    int s    = t >> 6;
    int sub  = t & 63;
    int part = sub >> 5;    // 0=q, 1=k
    int rh   = sub & 31;
    float* p = qkv + (size_t)s * 3072 + part * E_DIM + rh * D_DIM;
    const float* ct = tab + s * 8;
    const float* st = tab + 16384 + s * 8;

    float v[16];
#pragma unroll
    for (int i = 0; i < 4; ++i) *(float4*)(v + i * 4) = *(const float4*)(p + i * 4);
    float o[16];
#pragma unroll
    for (int pi = 0; pi < 8; ++pi) {
        float c = ct[pi], sn = st[pi];
        float x1 = v[2 * pi], x2 = v[2 * pi + 1];
        o[2 * pi]     = x1 * c - x2 * sn;
        o[2 * pi + 1] = x2 * c + x1 * sn;
    }
    if (rh & 1) {
#pragma unroll
        for (int i = 0; i < 16; ++i) o[i] += sig[i];
        float u[16];
#pragma unroll
        for (int i = 0; i < 4; ++i) *(float4*)(u + i * 4) = *(const float4*)(p + 16 + i * 4);
#pragma unroll
        for (int i = 0; i < 16; ++i) u[i] += sig[16 + i];
#pragma unroll
        for (int i = 0; i < 4; ++i) *(float4*)(p + 16 + i * 4) = *(const float4*)(u + i * 4);
    }
#pragma unroll
    for (int i = 0; i < 4; ++i) *(float4*)(p + i * 4) = *(const float4*)(o + i * 4);
}

// ---------------------------------------------------------------------------
// MFMA flash attention v2: double-buffered K/V LDS, T14 register prefetch of
// tile t+1 overlapped with compute of tile t, ONE barrier per tile.
// Dispatch: virt = (phys&7)*128 + phys>>3 clusters 4 heads per XCD (L2);
// rb = LPT interleave (big q-tiles dispatched first).
// Block = 256 thr (4 waves) = one (a,h), one 64-row q-tile. Wave wq: 16 rows.
// K -> bf16 LDS [64key][32d] (xor-swz 16B slots), V -> bf16 LDS transposed
// [64d][64k] (xor-swz). QK^T = 4 MFMA 16x16x32; online softmax in C-layout;
// P -> bf16 -> per-wave LDS (same-wave transpose, lgkmcnt+sched_barrier);
// PV = 8 MFMA. Scale folded into Q conversion.
// C/D layout: col=lane&15, row=(lane>>4)*4+reg (verified m89/m91).
// ---------------------------------------------------------------------------
__global__ __launch_bounds__(256, 2) void fattn_kernel(
    const float* __restrict__ qkv, float* __restrict__ attn)
{
    __shared__ __bf16 Ks[2][2048];   // [64key][32d], 16B slot s=key*4+ds, stored s^((key>>1)&3)
    __shared__ __bf16 Vt[2][4096];   // [64d][64k], elem (d*64+k)^((d&7)<<3)
    __shared__ __bf16 Pl[4096];      // 4 waves x [16q][64k], elem (q*64+k)^((q&7)<<3)

    const int phys = blockIdx.x;                    // 0..1023
    const int virt = (phys & 7) * 128 + (phys >> 3);  // XCD-clustered
    const int ah = virt >> 5;
    const int u  = virt & 31;
    const int rb = (u & 1) ? (u >> 1) : (31 - (u >> 1));  // LPT: big first
    const int h = ah >> 1;
    const int a = ah & 1;
    const int rh = 2 * h + a;
    const int i0 = rb * 64;
    const int tid = threadIdx.x;
    const int wq = tid >> 6;
    const int lane = tid & 63;
    const int c = lane & 15;
    const int g = lane >> 4;

    // Q fragment: rows i0+wq*16+c, d = g*8..+8, scale folded in.
    const float scale = 0.17677669529663687f;  // 32^-0.5
    const float* qp = qkv + (size_t)(i0 + wq * 16 + c) * 3072 + rh * 32 + g * 8;
    float4 q0 = *(const float4*)qp;
    float4 q1 = *(const float4*)(qp + 4);
    v8bf qf;
    qf[0] = (__bf16)(q0.x * scale); qf[1] = (__bf16)(q0.y * scale);
    qf[2] = (__bf16)(q0.z * scale); qf[3] = (__bf16)(q0.w * scale);
    qf[4] = (__bf16)(q1.x * scale); qf[5] = (__bf16)(q1.y * scale);
    qf[6] = (__bf16)(q1.z * scale); qf[7] = (__bf16)(q1.w * scale);

    f32x4 o_acc[4];
#pragma unroll
    for (int nj = 0; nj < 4; ++nj) o_acc[nj] = (f32x4){0.f, 0.f, 0.f, 0.f};
    float m_run[4] = {-3.0e38f, -3.0e38f, -3.0e38f, -3.0e38f};
    float l_run[4] = {0.f, 0.f, 0.f, 0.f};

    // staging assignments
    const int sk_key = tid >> 2, sk_ds = tid & 3;     // K: row, 8-d slice
    const int sk_slot = (((sk_key * 4 + sk_ds) ^ ((sk_key >> 1) & 3)) * 8);
    const int sv_k = tid >> 2, sv_dg = tid & 3;       // V: row, 16-d group
    const int pbase = wq * 1024;
    const float* kbase = qkv + E_DIM + rh * 32 + sk_ds * 8;
    const float* vbase = qkv + 2 * E_DIM + h * 64 + sv_dg * 16;

    // ---- prologue: stage tile 0 into buf 0 ----
    {
        const float* ksrc = kbase + (size_t)sk_key * 3072;
        float4 pk0 = *(const float4*)ksrc;
        float4 pk1 = *(const float4*)(ksrc + 4);
        const float* vsrc = vbase + (size_t)sv_k * 3072;
        float4 pv0 = *(const float4*)vsrc;
        float4 pv1 = *(const float4*)(vsrc + 4);
        float4 pv2 = *(const float4*)(vsrc + 8);
        float4 pv3 = *(const float4*)(vsrc + 12);
        v8bf kb;
        kb[0] = (__bf16)pk0.x; kb[1] = (__bf16)pk0.y; kb[2] = (__bf16)pk0.z; kb[3] = (__bf16)pk0.w;
        kb[4] = (__bf16)pk1.x; kb[5] = (__bf16)pk1.y; kb[6] = (__bf16)pk1.z; kb[7] = (__bf16)pk1.w;
        *(v8bf*)&Ks[0][sk_slot] = kb;
        float vv[16] = {pv0.x, pv0.y, pv0.z, pv0.w, pv1.x, pv1.y, pv1.z, pv1.w,
                        pv2.x, pv2.y, pv2.z, pv2.w, pv3.x, pv3.y, pv3.z, pv3.w};
#pragma unroll
        for (int e = 0; e < 16; ++e) {
            int d = sv_dg * 16 + e;
            Vt[0][(d * 64 + sv_k) ^ ((d & 7) << 3)] = (__bf16)vv[e];
        }
    }
    __syncthreads();

    for (int jt = 0; jt <= rb; ++jt) {
        const int cur = jt & 1;
        // ---- T14: issue next-tile global loads (clamped to 0 on last iter) --
        const int jn = (jt < rb) ? (jt + 1) * 64 : 0;
        const float* ksrc = kbase + (size_t)(jn + sk_key) * 3072;
        float4 pk0 = *(const float4*)ksrc;
        float4 pk1 = *(const float4*)(ksrc + 4);
        const float* vsrc = vbase + (size_t)(jn + sv_k) * 3072;
        float4 pv0 = *(const float4*)vsrc;
        float4 pv1 = *(const float4*)(vsrc + 4);
        float4 pv2 = *(const float4*)(vsrc + 8);
        float4 pv3 = *(const float4*)(vsrc + 12);

        // ---- QK^T: 4 MFMA over key groups (from buf cur) ----
        f32x4 s[4];
#pragma unroll
        for (int ni = 0; ni < 4; ++ni) {
            int slot = ((((16 * ni + c) * 4 + g) ^ ((c >> 1) & 3)) * 8);
            v8bf kf = *(const v8bf*)&Ks[cur][slot];
            s[ni] = __builtin_amdgcn_mfma_f32_16x16x32_bf16(
                qf, kf, (f32x4){0.f, 0.f, 0.f, 0.f}, 0, 0, 0);
        }
        // diagonal-tile causal mask: key_local(16ni+c) > q_local(wq*16+4g+r)
        if (jt == rb) {
#pragma unroll
            for (int ni = 0; ni < 4; ++ni)
#pragma unroll
                for (int r = 0; r < 4; ++r)
                    if (16 * ni + c > wq * 16 + 4 * g + r) s[ni][r] = -3.0e38f;
        }

        // ---- online softmax (per reg r = one query row) ----
        float p[4][4];
#pragma unroll
        for (int r = 0; r < 4; ++r) {
            float t = fmaxf(fmaxf(s[0][r], s[1][r]), fmaxf(s[2][r], s[3][r]));
            t = fmaxf(t, __shfl_xor(t, 1, 64));
            t = fmaxf(t, __shfl_xor(t, 2, 64));
            t = fmaxf(t, __shfl_xor(t, 4, 64));
            t = fmaxf(t, __shfl_xor(t, 8, 64));
            float mnew = fmaxf(m_run[r], t);
            float corr = __expf(m_run[r] - mnew);
            m_run[r] = mnew;
            l_run[r] *= corr;
#pragma unroll
            for (int nj = 0; nj < 4; ++nj) o_acc[nj][r] *= corr;
#pragma unroll
            for (int ni = 0; ni < 4; ++ni) {
                float pp = __expf(s[ni][r] - mnew);
                p[ni][r] = pp;
                l_run[r] += pp;
            }
        }

        // ---- P -> bf16 -> per-wave LDS (C-layout -> A-frag transpose) ----
#pragma unroll
        for (int ni = 0; ni < 4; ++ni)
#pragma unroll
            for (int r = 0; r < 4; ++r) {
                int q = 4 * g + r;
                Pl[pbase + ((q * 64 + 16 * ni + c) ^ ((q & 7) << 3))] = (__bf16)p[ni][r];
            }
        asm volatile("s_waitcnt lgkmcnt(0)" ::: "memory");
        __builtin_amdgcn_sched_barrier(0);

        // ---- PV: O[16q x 64d] += P[16 x 64] @ V[64 x 64] (from buf cur) ----
        v8bf pa[2];
#pragma unroll
        for (int kj = 0; kj < 2; ++kj)
            pa[kj] = *(const v8bf*)&Pl[pbase + ((c * 64 + kj * 32 + g * 8) ^ ((c & 7) << 3))];
#pragma unroll
        for (int nj = 0; nj < 4; ++nj) {
            int d = 16 * nj + c;
#pragma unroll
            for (int kj = 0; kj < 2; ++kj) {
                v8bf vb = *(const v8bf*)&Vt[cur][(d * 64 + kj * 32 + g * 8) ^ ((c & 7) << 3)];
                o_acc[nj] = __builtin_amdgcn_mfma_f32_16x16x32_bf16(
                    pa[kj], vb, o_acc[nj], 0, 0, 0);
            }
        }

        // ---- write prefetched tile into the other buffer, then publish ----
        {
            v8bf kb;
            kb[0] = (__bf16)pk0.x; kb[1] = (__bf16)pk0.y; kb[2] = (__bf16)pk0.z; kb[3] = (__bf16)pk0.w;
            kb[4] = (__bf16)pk1.x; kb[5] = (__bf16)pk1.y; kb[6] = (__bf16)pk1.z; kb[7] = (__bf16)pk1.w;
            *(v8bf*)&Ks[cur ^ 1][sk_slot] = kb;
            float vv[16] = {pv0.x, pv0.y, pv0.z, pv0.w, pv1.x, pv1.y, pv1.z, pv1.w,
                            pv2.x, pv2.y, pv2.z, pv2.w, pv3.x, pv3.y, pv3.z, pv3.w};
#pragma unroll
            for (int e = 0; e < 16; ++e) {
                int d = sv_dg * 16 + e;
                Vt[cur ^ 1][(d * 64 + sv_k) ^ ((d & 7) << 3)] = (__bf16)vv[e];
            }
        }
        __syncthreads();
    }

    // epilogue: row-sum of l, normalize, store f32
#pragma unroll
    for (int r = 0; r < 4; ++r) {
        float lt = l_run[r];
        lt += __shfl_xor(lt, 1, 64);
        lt += __shfl_xor(lt, 2, 64);
        lt += __shfl_xor(lt, 4, 64);
        lt += __shfl_xor(lt, 8, 64);
        l_run[r] = 1.0f / lt;
    }
#pragma unroll
    for (int nj = 0; nj < 4; ++nj)
#pragma unroll
        for (int r = 0; r < 4; ++r) {
            int qg = i0 + wq * 16 + 4 * g + r;
            attn[((size_t)a * S_LEN + qg) * E_DIM + h * 64 + 16 * nj + c] =
                o_acc[nj][r] * l_run[r];
        }
}

// ---------------------------------------------------------------------------
// diff + rmsnorm -> bf16 (unchanged).
// ---------------------------------------------------------------------------
__global__ __launch_bounds__(256) void diffnorm_kernel(
    const float* __restrict__ attn, const float* __restrict__ ln_w,
    const float* __restrict__ ln_b, const float* __restrict__ lamp,
    __bf16* __restrict__ out)
{
    int g = blockIdx.x * 4 + (threadIdx.x >> 6);   // 0..32767
    int lane = threadIdx.x & 63;
    int s = g >> 4;
    int h = g & 15;
    float lam = lamp[0];
    const float* p1 = attn + (size_t)s * E_DIM + h * 64;
    const float* p2 = attn + (size_t)(S_LEN + s) * E_DIM + h * 64;
    float c = p1[lane] - lam * p2[lane];
    float sq = c * c;
#pragma unroll
    for (int off = 32; off >= 1; off >>= 1) sq += __shfl_xor(sq, off, 64);
    float ms = sq * (1.0f / 64.0f);
    float r = 1.0f / sqrtf(ms + 1e-8f);
    float o = (c * r * ln_w[lane] + ln_b[lane]) * ONE_MINUS_LAMBDA_INIT;
    out[(size_t)s * E_DIM + h * 64 + lane] = (__bf16)o;
}

// ---------------------------------------------------------------------------
// LayerNorm over E=1024 (unchanged).
// ---------------------------------------------------------------------------
__global__ __launch_bounds__(256) void ln_kernel(
    const float* __restrict__ in, const float* __restrict__ w,
    const float* __restrict__ b, float* __restrict__ out,
    __bf16* __restrict__ outb)
{
    __shared__ float red[4];
    int row = blockIdx.x;
    int t = threadIdx.x;
    const float* xr = in + (size_t)row * E_DIM + t * 4;
    float4 v = *(const float4*)xr;
    float s = v.x + v.y + v.z + v.w;
#pragma unroll
    for (int off = 32; off >= 1; off >>= 1) s += __shfl_xor(s, off, 64);
    if ((t & 63) == 0) red[t >> 6] = s;
    __syncthreads();
    float mu = (red[0] + red[1] + red[2] + red[3]) * (1.0f / 1024.0f);
    __syncthreads();
    float dx0 = v.x - mu, dx1 = v.y - mu, dx2 = v.z - mu, dx3 = v.w - mu;
    float sq = dx0 * dx0 + dx1 * dx1 + dx2 * dx2 + dx3 * dx3;
#pragma unroll
    for (int off = 32; off >= 1; off >>= 1) sq += __shfl_xor(sq, off, 64);
    if ((t & 63) == 0) red[t >> 6] = sq;
    __syncthreads();
    float var = (red[0] + red[1] + red[2] + red[3]) * (1.0f / 1024.0f);
    float r = 1.0f / sqrtf(var + 1e-5f);
    float4 wv = *(const float4*)(w + t * 4);
    float4 bv = *(const float4*)(b + t * 4);
    float4 o;
    o.x = dx0 * r * wv.x + bv.x;
    o.y = dx1 * r * wv.y + bv.y;
    o.z = dx2 * r * wv.z + bv.z;
    o.w = dx3 * r * wv.w + bv.w;
    *(float4*)(out + (size_t)row * E_DIM + t * 4) = o;
    if (outb) {
        v4bf ob;
        ob[0] = (__bf16)o.x; ob[1] = (__bf16)o.y;
        ob[2] = (__bf16)o.z; ob[3] = (__bf16)o.w;
        *(v4bf*)(outb + (size_t)row * E_DIM + t * 4) = ob;
    }
}

// ---------------------------------------------------------------------------
extern "C" void kernel_launch(void* const* d_in, const int* in_sizes, int n_in,
                              void* d_out, int out_size, void* d_ws, size_t ws_size,
                              hipStream_t stream)
{
    const float* x       = (const float*)d_in[0];
    const float* emb     = (const float*)d_in[1];
    const float* qkv_w   = (const float*)d_in[2];
    const float* out_w   = (const float*)d_in[3];
    const float* sigma_w = (const float*)d_in[4];
    const float* lq1     = (const float*)d_in[5];
    const float* lk1     = (const float*)d_in[6];
    const float* lq2     = (const float*)d_in[7];
    const float* lk2     = (const float*)d_in[8];
    const float* ln_w    = (const float*)d_in[9];
    const float* ln_b    = (const float*)d_in[10];
    const float* ln1_w   = (const float*)d_in[11];
    const float* ln1_b   = (const float*)d_in[12];
    const float* ln2_w   = (const float*)d_in[13];
    const float* ln2_b   = (const float*)d_in[14];
    const float* w1      = (const float*)d_in[15];
    const float* b1      = (const float*)d_in[16];
    const float* w2      = (const float*)d_in[17];
    const float* b2      = (const float*)d_in[18];
    float* out = (float*)d_out;
    char* ws = (char*)d_ws;

    float*  qkv  = (float*)(ws + B_QKV);
    __bf16* g    = (__bf16*)(ws + B_G);
    __bf16* xb   = (__bf16*)(ws + B_XB);
    float*  attn = (float*)(ws + B_ATTN);
    float*  t1   = (float*)(ws + B_T1);
    __bf16* hb   = (__bf16*)(ws + B_HB);
    float*  t2   = (float*)(ws + B_T2);
    __bf16* anrm = (__bf16*)(ws + B_ANRM);
    float*  hbuf = (float*)(ws + B_HBUF);
    __bf16* qwb  = (__bf16*)(ws + B_QWB);
    __bf16* owb  = (__bf16*)(ws + B_OWB);
    __bf16* w1b  = (__bf16*)(ws + B_W1B);
    __bf16* w2b  = (__bf16*)(ws + B_W2B);
    float*  tab  = (float*)(ws + B_TAB);
    float*  sig  = tab + 32768;
    float*  lam  = tab + 32800;

    // 1. tables + sig/lam
    tab_kernel<<<64, 256, 0, stream>>>(tab);
    sig_lam_kernel<<<1, 64, 0, stream>>>(emb, sigma_w, lq1, lk1, lq2, lk2, sig, lam);
    // 2. bf16 conversions for GEMM1
    f2b_kernel<<<1024, 256, 0, stream>>>(x, xb, 2097152);
    f2b_kernel<<<1536, 256, 0, stream>>>(qkv_w, qwb, 3145728);
    // 3. qkv = x @ qkv_w^T   (2048 x 3072 x 1024)
    mgemm_kernel<false, false, false, false><<<dim3(24, 16), 256, 0, stream>>>(
        xb, qwb, qkv, (__bf16*)0, 2048, 3072, 1024, (const float*)0, (const float*)0);
    // 4. RoPE + sigma
    rope_kernel<<<512, 256, 0, stream>>>(qkv, tab, sig);
    // 5. dual causal attention (MFMA flash v2)
    fattn_kernel<<<1024, 256, 0, stream>>>(qkv, attn);
    // 6. diff + rmsnorm -> bf16
    diffnorm_kernel<<<8192, 256, 0, stream>>>(attn, ln_w, ln_b, lam, anrm);
    // 7. out_w -> bf16 (qkv region now dead)
    f2b_kernel<<<512, 256, 0, stream>>>(out_w, owb, 1048576);
    // 8. t1 = anrm @ out_w^T + x   (2048 x 1024 x 1024)
    mgemm_kernel<false, false, true, false><<<dim3(8, 16), 256, 0, stream>>>(
        anrm, owb, t1, (__bf16*)0, 2048, 1024, 1024, (const float*)0, x);
    // 9. h = layernorm(t1)  (fp32 + bf16)
    ln_kernel<<<2048, 256, 0, stream>>>(t1, ln1_w, ln1_b, hbuf, hb);
    // 10. w1 -> bf16
    f2b_kernel<<<2048, 256, 0, stream>>>(w1, w1b, 4194304);
    // 11. g = silu(h @ w1^T + b1) -> bf16   (2048 x 4096 x 1024)
    mgemm_kernel<true, true, false, true><<<dim3(32, 16), 256, 0, stream>>>(
        hb, w1b, (float*)0, g, 2048, 4096, 1024, b1, (const float*)0);
    // 12. w2 -> bf16
    f2b_kernel<<<2048, 256, 0, stream>>>(w2, w2b, 4194304);
    // 13. t2 = g @ w2^T + b2 + h   (2048 x 1024 x 4096)
    mgemm_kernel<true, false, true, false><<<dim3(8, 16), 256, 0, stream>>>(
        g, w2b, t2, (__bf16*)0, 2048, 1024, 4096, b2, hbuf);
    // 14. out = layernorm(t2)
    ln_kernel<<<2048, 256, 0, stream>>>(t2, ln2_w, ln2_b, out, (__bf16*)0);
}